// Round 1
// 265.297 us; speedup vs baseline: 1.2460x; 1.2460x over previous
//
#include <hip/hip_runtime.h>
#include <hip/hip_bf16.h>

#define D 128            // D_IN == D_OUT == 128
#define D4 32            // D/4 float4s per row
#define CHUNK 3072       // edges per hist / bscatter block (1024 threads)
#define MAXB 2048        // max buckets => n_nodes <= 131072 for fast path
#define NSEG 8           // column-sum segments over the chunk axis

typedef __attribute__((ext_vector_type(8))) short bf16x8;
typedef __attribute__((ext_vector_type(4))) float f32x4;

// float -> bf16 round-to-nearest-even
static __device__ __forceinline__ unsigned short f2bf(float f) {
    unsigned u = __float_as_uint(f);
    u += 0x7FFFu + ((u >> 16) & 1u);
    return (unsigned short)(u >> 16);
}
static __device__ __forceinline__ float bf2f(unsigned short u) {
    return __uint_as_float(((unsigned)u) << 16);
}

// ---------------------------------------------------------------------------
// GEMM via bf16 MFMA: hwb[n,:] = bf16( (h[n,:] @ W) * norm[n] )
// 64-row tile/block, 256 thr = 4 waves; wave w handles rows [w*16,w*16+16),
// 8 col-tiles x 4 k-steps of v_mfma_f32_16x16x32_bf16.
// LDS rows padded to 136 ushorts (+16B) to break b128 bank conflicts.
// ---------------------------------------------------------------------------
__global__ __launch_bounds__(256) void gemm_mfma_kernel(
    const float* __restrict__ h, const float* __restrict__ W,
    const float* __restrict__ norm, unsigned short* __restrict__ hwb,
    int n_nodes)
{
    __shared__ unsigned short As[64 * 136];    // [row][k] bf16, padded stride
    __shared__ unsigned short Bs[128 * 136];   // [col][k] bf16 (W^T), padded

    const int t = threadIdx.x;
    const int row0 = blockIdx.x * 64;

    #pragma unroll
    for (int i = 0; i < 16; ++i) {
        const int idx = t + 256 * i;           // float4 index over 128x32
        const int k = idx >> 5;
        const int c = (idx & 31) * 4;
        const float4 w = ((const float4*)W)[idx];
        Bs[(c + 0) * 136 + k] = f2bf(w.x);
        Bs[(c + 1) * 136 + k] = f2bf(w.y);
        Bs[(c + 2) * 136 + k] = f2bf(w.z);
        Bs[(c + 3) * 136 + k] = f2bf(w.w);
    }
    #pragma unroll
    for (int i = 0; i < 8; ++i) {
        const int idx = t + 256 * i;           // float4 index over 64x32
        const int r = idx >> 5;
        const int kq = idx & 31;
        long gr = row0 + r; if (gr >= n_nodes) gr = n_nodes - 1;
        const float4 a = ((const float4*)(h + gr * D))[kq];
        ushort4 o;
        o.x = f2bf(a.x); o.y = f2bf(a.y); o.z = f2bf(a.z); o.w = f2bf(a.w);
        *(ushort4*)&As[r * 136 + kq * 4] = o;
    }
    __syncthreads();

    const int wv = t >> 6;
    const int lane = t & 63;
    const int m = lane & 15;
    const int quad = lane >> 4;

    f32x4 acc[8];
    #pragma unroll
    for (int nt = 0; nt < 8; ++nt) { f32x4 z = {0.f, 0.f, 0.f, 0.f}; acc[nt] = z; }

    #pragma unroll
    for (int kt = 0; kt < 4; ++kt) {
        const bf16x8 af = *(const bf16x8*)&As[(wv * 16 + m) * 136 + kt * 32 + quad * 8];
        #pragma unroll
        for (int nt = 0; nt < 8; ++nt) {
            const bf16x8 bfr = *(const bf16x8*)&Bs[(nt * 16 + m) * 136 + kt * 32 + quad * 8];
            acc[nt] = __builtin_amdgcn_mfma_f32_16x16x32_bf16(af, bfr, acc[nt], 0, 0, 0);
        }
    }

    float nv[4];
    #pragma unroll
    for (int i = 0; i < 4; ++i) {
        const int gr = row0 + wv * 16 + quad * 4 + i;
        nv[i] = (gr < n_nodes) ? norm[gr] : 0.f;
    }
    #pragma unroll
    for (int nt = 0; nt < 8; ++nt) {
        #pragma unroll
        for (int i = 0; i < 4; ++i) {
            const int gr = row0 + wv * 16 + quad * 4 + i;
            if (gr < n_nodes)
                hwb[(size_t)gr * D + nt * 16 + m] = f2bf(acc[nt][i] * nv[i]);
        }
    }
}

// ---------------------------------------------------------------------------
// hist (1024 thr, CHUNK edges): LDS bucket histogram only -> persists its
// hist row H[g][*] (coalesced). NO global atomics. Block 0 zeroes the dummy
// hwb row used by aggregation padding.
// ---------------------------------------------------------------------------
__global__ __launch_bounds__(1024) void hist_kernel(
    const int* __restrict__ dst, int* __restrict__ H,
    unsigned short* __restrict__ hwb, int n_edges, int n_nodes)
{
    __shared__ int lbh[MAXB];
    const int t = threadIdx.x;
    const int g = blockIdx.x;
    for (int i = t; i < MAXB; i += 1024) lbh[i] = 0;
    if (g == 0 && t < 32) {
        ushort4 z; z.x = z.y = z.z = z.w = 0;
        ((ushort4*)(hwb + (size_t)n_nodes * D))[t] = z;
    }
    __syncthreads();
    const int e0 = g * CHUNK;
    const int e1 = min(e0 + CHUNK, n_edges);
    for (int e = e0 + t; e < e1; e += 1024) {
        atomicAdd(&lbh[dst[e] >> 6], 1);
    }
    __syncthreads();
    for (int i = t; i < MAXB; i += 1024) {
        H[(size_t)g * MAXB + i] = lbh[i];
    }
}

// ---------------------------------------------------------------------------
// colsum: segmented column sums of H -> PS[seg][bucket]. Replaces the
// fire-and-forget bcnt atomics. Fully coalesced reads (1KB/row-iter/block).
// ---------------------------------------------------------------------------
__global__ __launch_bounds__(256) void colsum_kernel(
    const int* __restrict__ H, int* __restrict__ PS, int eb)
{
    const int col = blockIdx.x * 256 + threadIdx.x;
    const int seg = blockIdx.y;
    const int glen = (eb + NSEG - 1) / NSEG;
    const int g0 = seg * glen;
    const int g1 = min(g0 + glen, eb);
    int s = 0;
    for (int g = g0; g < g1; ++g) s += H[(size_t)g * MAXB + col];
    PS[seg * MAXB + col] = s;
}

// ---------------------------------------------------------------------------
// bucket_scan (1 block, 256 thr x 8 buckets/thr): sum PS segments ->
// exclusive scan over MAXB bucket counts -> boff, bcur.
// ---------------------------------------------------------------------------
__global__ __launch_bounds__(256) void bucket_scan_kernel(
    const int* __restrict__ PS, int* __restrict__ boff, int* __restrict__ bcur)
{
    __shared__ int tmp[256];
    const int t = threadIdx.x;
    int v[8];
    int s = 0;
    #pragma unroll
    for (int k = 0; k < 8; ++k) {
        const int i = t * 8 + k;
        int c = 0;
        #pragma unroll
        for (int sg = 0; sg < NSEG; ++sg) c += PS[sg * MAXB + i];
        v[k] = c; s += c;
    }
    tmp[t] = s;
    __syncthreads();
    for (int ofs = 1; ofs < 256; ofs <<= 1) {
        int x = (t >= ofs) ? tmp[t - ofs] : 0;
        __syncthreads();
        tmp[t] += x;
        __syncthreads();
    }
    int run = tmp[t] - s;
    #pragma unroll
    for (int k = 0; k < 8; ++k) {
        boff[t * 8 + k] = run;
        bcur[t * 8 + k] = run;
        run += v[k];
    }
    if (t == 255) boff[MAXB] = run;
}

// ---------------------------------------------------------------------------
// bscatter (1024 thr): load own hist row H[g][*], reserve bucket windows via
// returning atomics, then LDS-ranked scatter of packed records
// (src | (dst&63)<<17) into bucket-major ebuf.
// ---------------------------------------------------------------------------
__global__ __launch_bounds__(1024) void bscatter_kernel(
    const int* __restrict__ src, const int* __restrict__ dst,
    const int* __restrict__ H, int* __restrict__ bcur,
    unsigned int* __restrict__ ebuf, int n_edges)
{
    __shared__ int lbh[MAXB];
    __shared__ int lofs[MAXB];
    const int t = threadIdx.x;
    const int g = blockIdx.x;
    for (int i = t; i < MAXB; i += 1024) {
        lbh[i] = 0;
        const int c = H[(size_t)g * MAXB + i];
        lofs[i] = c ? atomicAdd(&bcur[i], c) : 0;
    }
    __syncthreads();
    const int e0 = g * CHUNK;
    const int e1 = min(e0 + CHUNK, n_edges);
    for (int e = e0 + t; e < e1; e += 1024) {
        const int d = dst[e];
        const int bk = d >> 6;
        const int r = atomicAdd(&lbh[bk], 1);
        ebuf[lofs[bk] + r] = (unsigned)src[e] | ((unsigned)(d & 63) << 17);
    }
}

// ---------------------------------------------------------------------------
// fill_local: one block per bucket (64 nodes). Pass A: count the bucket's 64
// node degrees from its contiguous ebuf window (LDS counters only). Then a
// 64-lane wave scan produces padded per-node offsets with bucket-local base
// boff[b] + 448*b (448 = 64 nodes x max 7 pad slots), writing cnt/off for the
// aggregation kernel -- this replaces 1.6M global cnt atomics AND the whole
// per-node global scan chain. Pass B: ranked scatter of srcs + dummy pads.
// ---------------------------------------------------------------------------
__global__ __launch_bounds__(256) void fill_local_kernel(
    const unsigned int* __restrict__ ebuf, const int* __restrict__ boff,
    int* __restrict__ off, int* __restrict__ cnt,
    int* __restrict__ srcs, int n_nodes)
{
    __shared__ int lcnt[64];
    __shared__ int lcur[64];
    __shared__ int loff[64];
    const int t = threadIdx.x;
    const int b = blockIdx.x;
    const int gn0 = b * 64;
    if (t < 64) lcnt[t] = 0;
    __syncthreads();
    const int e0 = boff[b], e1 = boff[b + 1];
    for (int e = e0 + t; e < e1; e += 256) {
        atomicAdd(&lcnt[(ebuf[e] >> 17) & 63], 1);
    }
    __syncthreads();
    if (t < 64) {
        const int c = lcnt[t];
        const int p = (c + 7) & ~7;          // pad degree to x8
        int x = p;
        #pragma unroll
        for (int ofs = 1; ofs < 64; ofs <<= 1) {
            const int y = __shfl_up(x, ofs, 64);
            if (t >= ofs) x += y;
        }
        const int base = boff[b] + b * 448 + (x - p);  // exclusive padded scan
        lcur[t] = base;
        loff[t] = base;
        const int gn = gn0 + t;
        if (gn < n_nodes) { cnt[gn] = c; off[gn] = base; }
    }
    __syncthreads();
    for (int e = e0 + t; e < e1; e += 256) {
        const unsigned rec = ebuf[e];
        const int loc = (rec >> 17) & 63;
        const int pos = atomicAdd(&lcur[loc], 1);
        srcs[pos] = (int)(rec & 0x1FFFFu);
    }
    for (int w = t; w < 512; w += 256) {
        const int ln = w >> 3, k = w & 7;
        const int gn = gn0 + ln;
        if (gn < n_nodes) {
            const int c = lcnt[ln];
            const int pad = (8 - (c & 7)) & 7;
            if (k < pad) srcs[loff[ln] + c + k] = n_nodes;
        }
    }
}

// ---------------------------------------------------------------------------
// Aggregation: 8 nodes/block, 32 lanes/node, ushort4 bf16 gathers, MLP=8 via
// x8 segment padding. Fuses out = agg*norm + bias.
// ---------------------------------------------------------------------------
__global__ __launch_bounds__(256) void agg_kernel(
    const unsigned short* __restrict__ hwb, const int* __restrict__ srcs,
    const int* __restrict__ off, const int* __restrict__ cnt,
    const float* __restrict__ norm, const float* __restrict__ bias,
    float* __restrict__ out, int n_nodes)
{
    const int t = threadIdx.x;
    const int sub = t >> 5;
    const int lane32 = t & 31;
    const int node = blockIdx.x * 8 + sub;
    if (node >= n_nodes) return;

    const int start = off[node];
    const int deg = cnt[node];
    const int nb8 = (deg + 7) >> 3;

    const ushort4* hw4 = (const ushort4*)hwb;

    float4 acc; acc.x = acc.y = acc.z = acc.w = 0.0f;
    int myidx = 0;

    for (int b = 0; b < nb8; ++b) {
        const int q = b & 3;
        if (q == 0) myidx = srcs[start + b * 8 + lane32];
        ushort4 v[8];
        #pragma unroll
        for (int jj = 0; jj < 8; ++jj) {
            const int s = __shfl(myidx, q * 8 + jj, 32);
            v[jj] = hw4[(long)s * D4 + lane32];
        }
        #pragma unroll
        for (int jj = 0; jj < 8; ++jj) {
            acc.x += bf2f(v[jj].x);
            acc.y += bf2f(v[jj].y);
            acc.z += bf2f(v[jj].z);
            acc.w += bf2f(v[jj].w);
        }
    }

    const float nv = norm[node];
    const float4 bs = ((const float4*)bias)[lane32];
    float4 o;
    o.x = acc.x * nv + bs.x;
    o.y = acc.y * nv + bs.y;
    o.z = acc.z * nv + bs.z;
    o.w = acc.w * nv + bs.w;
    ((float4*)out)[(long)node * D4 + lane32] = o;
}

// ---------------------------------------------------------------------------
// Fallback path: atomic scatter from bf16 hwb + finalize (ws too small).
// ---------------------------------------------------------------------------
__global__ __launch_bounds__(256) void scatter_kernel(
    const unsigned short* __restrict__ hwb, const int* __restrict__ src,
    const int* __restrict__ dst, float* __restrict__ out, int n_edges)
{
    const int idx = blockIdx.x * 256 + threadIdx.x;
    if (idx >= n_edges * D4) return;
    const int e = idx >> 5;
    const int g = idx & 31;
    const int s = src[e];
    const int d = dst[e];
    const ushort4 v = ((const ushort4*)hwb)[(long)s * D4 + g];
    float* o = out + (long)d * D + g * 4;
    atomicAdd(o + 0, bf2f(v.x));
    atomicAdd(o + 1, bf2f(v.y));
    atomicAdd(o + 2, bf2f(v.z));
    atomicAdd(o + 3, bf2f(v.w));
}

__global__ __launch_bounds__(256) void finalize_kernel(
    float* __restrict__ out, const float* __restrict__ norm,
    const float* __restrict__ bias, int n_nodes)
{
    const int idx = blockIdx.x * 256 + threadIdx.x;
    if (idx >= n_nodes * D4) return;
    const int n = idx >> 5;
    const int g = idx & 31;
    float4 v = ((float4*)out)[idx];
    const float nv = norm[n];
    const float4 b = ((const float4*)bias)[g];
    v.x = v.x * nv + b.x;
    v.y = v.y * nv + b.y;
    v.z = v.z * nv + b.z;
    v.w = v.w * nv + b.w;
    ((float4*)out)[idx] = v;
}

extern "C" void kernel_launch(void* const* d_in, const int* in_sizes, int n_in,
                              void* d_out, int out_size, void* d_ws, size_t ws_size,
                              hipStream_t stream) {
    const float* h    = (const float*)d_in[0];
    const float* norm = (const float*)d_in[1];
    const int*   src  = (const int*)d_in[2];
    const int*   dst  = (const int*)d_in[3];
    const float* W    = (const float*)d_in[4];
    const float* bias = (const float*)d_in[5];
    float* out = (float*)d_out;

    const int n_nodes = in_sizes[1];
    const int n_edges = in_sizes[2];

    const int NBUCK = (n_nodes + 63) >> 6;           // buckets (64 nodes each)
    const int EB    = (n_edges + CHUNK - 1) / CHUNK; // edge chunks
    const int srcs_len = n_edges + 448 * NBUCK + 64; // bucket-local pad bound

    // ---- workspace layout (256B aligned) ----
    size_t p = 0;
    auto take = [&](size_t bytes) {
        size_t cur = p;
        p += (bytes + 255) & ~(size_t)255;
        return cur;
    };
    const size_t hwb_off  = take(((size_t)n_nodes + 1) * D * sizeof(unsigned short));
    const size_t cnt_off  = take((size_t)n_nodes * sizeof(int));
    const size_t off_off  = take((size_t)n_nodes * sizeof(int));
    const size_t srcs_off = take((size_t)srcs_len * sizeof(int));
    const size_t ebuf_off = take((size_t)n_edges * sizeof(unsigned int));
    const size_t boff_off = take((MAXB + 1) * sizeof(int));
    const size_t bcur_off = take(MAXB * sizeof(int));
    const size_t H_off    = take((size_t)EB * MAXB * sizeof(int));
    const size_t PS_off   = take((size_t)NSEG * MAXB * sizeof(int));
    const size_t needed = p;

    char* ws = (char*)d_ws;
    unsigned short* hwb = (unsigned short*)(ws + hwb_off);

    // 1) hwb = bf16((h @ W) * norm) via MFMA
    gemm_mfma_kernel<<<(n_nodes + 63) / 64, 256, 0, stream>>>(h, W, norm, hwb, n_nodes);

    if (ws_size >= needed && NBUCK <= MAXB && n_nodes <= 131072) {
        int* cnt   = (int*)(ws + cnt_off);
        int* off   = (int*)(ws + off_off);
        int* srcs  = (int*)(ws + srcs_off);
        unsigned int* ebuf = (unsigned int*)(ws + ebuf_off);
        int* boff  = (int*)(ws + boff_off);
        int* bcur  = (int*)(ws + bcur_off);
        int* H     = (int*)(ws + H_off);
        int* PS    = (int*)(ws + PS_off);

        hist_kernel<<<EB, 1024, 0, stream>>>(dst, H, hwb, n_edges, n_nodes);
        colsum_kernel<<<dim3(MAXB / 256, NSEG), 256, 0, stream>>>(H, PS, EB);
        bucket_scan_kernel<<<1, 256, 0, stream>>>(PS, boff, bcur);
        bscatter_kernel<<<EB, 1024, 0, stream>>>(src, dst, H, bcur, ebuf, n_edges);
        fill_local_kernel<<<NBUCK, 256, 0, stream>>>(ebuf, boff, off, cnt, srcs, n_nodes);
        agg_kernel<<<(n_nodes + 7) / 8, 256, 0, stream>>>(hwb, srcs, off, cnt, norm, bias,
                                                          out, n_nodes);
    } else {
        hipMemsetAsync(d_out, 0, (size_t)out_size * sizeof(float), stream);
        const int work = n_edges * D4;
        scatter_kernel<<<(work + 255) / 256, 256, 0, stream>>>(hwb, src, dst, out, n_edges);
        const int work2 = n_nodes * D4;
        finalize_kernel<<<(work2 + 255) / 256, 256, 0, stream>>>(out, norm, bias, n_nodes);
    }
}

// Round 2
// 263.509 us; speedup vs baseline: 1.2544x; 1.0068x over previous
//
#include <hip/hip_runtime.h>
#include <hip/hip_bf16.h>
#include <hip/hip_cooperative_groups.h>

namespace cg = cooperative_groups;

#define D 128            // D_IN == D_OUT == 128
#define D4 32            // D/4 float4s per row
#define CHUNK 3072       // edges per block, tier-2 path
#define CHUNK_C 3200     // edges per block, cooperative path (EB<=512 => co-resident)
#define KSLOT 4          // ceil(CHUNK_C/1024)
#define MAXB 2048        // max buckets => n_nodes <= 131072 for fast path
#define NSEG 8           // column-sum segments over the chunk axis
#define SLDS 8192        // LDS srcs-list capacity per bucket (ints)

typedef __attribute__((ext_vector_type(8))) short bf16x8;
typedef __attribute__((ext_vector_type(4))) float f32x4;

// float -> bf16 round-to-nearest-even
static __device__ __forceinline__ unsigned short f2bf(float f) {
    unsigned u = __float_as_uint(f);
    u += 0x7FFFu + ((u >> 16) & 1u);
    return (unsigned short)(u >> 16);
}
static __device__ __forceinline__ float bf2f(unsigned short u) {
    return __uint_as_float(((unsigned)u) << 16);
}

// ---------------------------------------------------------------------------
// GEMM via bf16 MFMA: hwb[n,:] = bf16( (h[n,:] @ W) * norm[n] )
// ---------------------------------------------------------------------------
__global__ __launch_bounds__(256) void gemm_mfma_kernel(
    const float* __restrict__ h, const float* __restrict__ W,
    const float* __restrict__ norm, unsigned short* __restrict__ hwb,
    int n_nodes)
{
    __shared__ unsigned short As[64 * 136];    // [row][k] bf16, padded stride
    __shared__ unsigned short Bs[128 * 136];   // [col][k] bf16 (W^T), padded

    const int t = threadIdx.x;
    const int row0 = blockIdx.x * 64;

    #pragma unroll
    for (int i = 0; i < 16; ++i) {
        const int idx = t + 256 * i;           // float4 index over 128x32
        const int k = idx >> 5;
        const int c = (idx & 31) * 4;
        const float4 w = ((const float4*)W)[idx];
        Bs[(c + 0) * 136 + k] = f2bf(w.x);
        Bs[(c + 1) * 136 + k] = f2bf(w.y);
        Bs[(c + 2) * 136 + k] = f2bf(w.z);
        Bs[(c + 3) * 136 + k] = f2bf(w.w);
    }
    #pragma unroll
    for (int i = 0; i < 8; ++i) {
        const int idx = t + 256 * i;           // float4 index over 64x32
        const int r = idx >> 5;
        const int kq = idx & 31;
        long gr = row0 + r; if (gr >= n_nodes) gr = n_nodes - 1;
        const float4 a = ((const float4*)(h + gr * D))[kq];
        ushort4 o;
        o.x = f2bf(a.x); o.y = f2bf(a.y); o.z = f2bf(a.z); o.w = f2bf(a.w);
        *(ushort4*)&As[r * 136 + kq * 4] = o;
    }
    __syncthreads();

    const int wv = t >> 6;
    const int lane = t & 63;
    const int m = lane & 15;
    const int quad = lane >> 4;

    f32x4 acc[8];
    #pragma unroll
    for (int nt = 0; nt < 8; ++nt) { f32x4 z = {0.f, 0.f, 0.f, 0.f}; acc[nt] = z; }

    #pragma unroll
    for (int kt = 0; kt < 4; ++kt) {
        const bf16x8 af = *(const bf16x8*)&As[(wv * 16 + m) * 136 + kt * 32 + quad * 8];
        #pragma unroll
        for (int nt = 0; nt < 8; ++nt) {
            const bf16x8 bfr = *(const bf16x8*)&Bs[(nt * 16 + m) * 136 + kt * 32 + quad * 8];
            acc[nt] = __builtin_amdgcn_mfma_f32_16x16x32_bf16(af, bfr, acc[nt], 0, 0, 0);
        }
    }

    float nv[4];
    #pragma unroll
    for (int i = 0; i < 4; ++i) {
        const int gr = row0 + wv * 16 + quad * 4 + i;
        nv[i] = (gr < n_nodes) ? norm[gr] : 0.f;
    }
    #pragma unroll
    for (int nt = 0; nt < 8; ++nt) {
        #pragma unroll
        for (int i = 0; i < 4; ++i) {
            const int gr = row0 + wv * 16 + quad * 4 + i;
            if (gr < n_nodes)
                hwb[(size_t)gr * D + nt * 16 + m] = f2bf(acc[nt][i] * nv[i]);
        }
    }
}

// ---------------------------------------------------------------------------
// TIER 1: single cooperative kernel for the entire edge pipeline.
// P1   per-chunk bucket hist (edges+ranks kept in registers)
// 2a   segmented column sums of H  -> PS
// 2b   block 0: bucket exclusive scan -> boff, per-seg bases -> SB
// 2c   chunk-offset matrix CO[g][b] (replaces returning atomics)
// P3   scatter packed recs into bucket-major ebuf (no atomics, deterministic)
// P4   per-bucket: count -> wave-scan -> ranked scatter into LDS srcs list
//      (global arena fallback) -> x8-padded register-acc aggregation -> out
// ---------------------------------------------------------------------------
__global__ __launch_bounds__(1024, 8) void coop_kernel(
    const int* __restrict__ src, const int* __restrict__ dst,
    int* __restrict__ H, int* __restrict__ PS, int* __restrict__ SB,
    int* __restrict__ boff, int* __restrict__ CO,
    unsigned int* __restrict__ ebuf, int* __restrict__ srcs_g,
    unsigned short* __restrict__ hwb,
    const float* __restrict__ norm, const float* __restrict__ bias,
    float* __restrict__ out,
    int n_edges, int n_nodes, int EB, int NBUCK)
{
    __shared__ int lbh[MAXB];
    __shared__ int tmp[1024];
    __shared__ int slds[SLDS];
    __shared__ int lcnt[64];
    __shared__ int lcur[64];
    __shared__ int loffL[64];

    cg::grid_group grid = cg::this_grid();
    const int t = threadIdx.x;
    const int g = blockIdx.x;
    const int gid = g * 1024 + t;
    const int glen = (EB + NSEG - 1) / NSEG;

    // ---- P1: histogram; keep (dst,src,rank) in registers ----
    for (int i = t; i < MAXB; i += 1024) lbh[i] = 0;
    if (g == 0 && t < 32) {
        ushort4 z; z.x = z.y = z.z = z.w = 0;
        ((ushort4*)(hwb + (size_t)n_nodes * D))[t] = z;   // dummy pad row
    }
    __syncthreads();
    const int e0 = g * CHUNK_C;
    const int e1 = min(e0 + CHUNK_C, n_edges);
    int ed[KSLOT], es[KSLOT], er[KSLOT];
    bool ok[KSLOT];
    #pragma unroll
    for (int k = 0; k < KSLOT; ++k) {
        const int e = e0 + t + 1024 * k;
        ok[k] = e < e1;
        if (ok[k]) {
            ed[k] = dst[e];
            es[k] = src[e];
            er[k] = atomicAdd(&lbh[ed[k] >> 6], 1);
        } else { ed[k] = 0; es[k] = 0; er[k] = 0; }
    }
    __syncthreads();
    for (int i = t; i < MAXB; i += 1024) H[(size_t)g * MAXB + i] = lbh[i];
    grid.sync();

    // ---- 2a: PS[seg][c] = sum of H over the segment's chunk rows ----
    if (gid < NSEG * MAXB) {
        const int seg = gid >> 11;
        const int c = gid & (MAXB - 1);
        const int g0 = seg * glen, g1 = min(g0 + glen, EB);
        int s = 0;
        for (int gg = g0; gg < g1; ++gg) s += H[(size_t)gg * MAXB + c];
        PS[seg * MAXB + c] = s;
    }
    grid.sync();

    // ---- 2b: block 0 scans bucket totals -> boff; per-seg bases -> SB ----
    if (g == 0) {
        const int cA = 2 * t, cB = 2 * t + 1;
        int va = 0, vb = 0;
        #pragma unroll
        for (int sg = 0; sg < NSEG; ++sg) { va += PS[sg * MAXB + cA]; vb += PS[sg * MAXB + cB]; }
        tmp[t] = va + vb;
        __syncthreads();
        for (int ofs = 1; ofs < 1024; ofs <<= 1) {
            const int x = (t >= ofs) ? tmp[t - ofs] : 0;
            __syncthreads();
            tmp[t] += x;
            __syncthreads();
        }
        const int run = tmp[t] - (va + vb);
        boff[cA] = run;
        boff[cB] = run + va;
        if (t == 1023) boff[MAXB] = tmp[1023];
        int sb = run;
        #pragma unroll
        for (int sg = 0; sg < NSEG; ++sg) { SB[sg * MAXB + cA] = sb; sb += PS[sg * MAXB + cA]; }
        sb = run + va;
        #pragma unroll
        for (int sg = 0; sg < NSEG; ++sg) { SB[sg * MAXB + cB] = sb; sb += PS[sg * MAXB + cB]; }
    }
    grid.sync();

    // ---- 2c: CO[g][c] = global base of (chunk g, bucket c) window ----
    if (gid < NSEG * MAXB) {
        const int seg = gid >> 11;
        const int c = gid & (MAXB - 1);
        const int g0 = seg * glen, g1 = min(g0 + glen, EB);
        int run = SB[seg * MAXB + c];
        for (int gg = g0; gg < g1; ++gg) {
            CO[(size_t)gg * MAXB + c] = run;
            run += H[(size_t)gg * MAXB + c];
        }
    }
    grid.sync();

    // ---- P3: atomic-free scatter into bucket-major ebuf ----
    for (int i = t; i < MAXB; i += 1024) lbh[i] = CO[(size_t)g * MAXB + i];
    __syncthreads();
    #pragma unroll
    for (int k = 0; k < KSLOT; ++k) {
        if (ok[k])
            ebuf[lbh[ed[k] >> 6] + er[k]] =
                (unsigned)es[k] | ((unsigned)(ed[k] & 63) << 17);
    }
    grid.sync();

    // ---- P4: per-bucket fill + aggregation ----
    const ushort4* hw4 = (const ushort4*)hwb;
    for (int bkt = g; bkt < NBUCK; bkt += gridDim.x) {
        __syncthreads();                        // protect LDS reuse across buckets
        if (t < 64) lcnt[t] = 0;
        __syncthreads();
        const int w0 = boff[bkt], w1 = boff[bkt + 1];
        const int wlen = w1 - w0;
        const bool uselds = (wlen + 480) <= SLDS;   // pads(448)+lookahead(32)
        const int gbase = w0 + 448 * bkt;           // global arena fallback base
        for (int e = w0 + t; e < w1; e += 1024)
            atomicAdd(&lcnt[(ebuf[e] >> 17) & 63], 1);
        __syncthreads();
        if (t < 64) {
            const int c = lcnt[t];
            const int p = (c + 7) & ~7;             // degree padded to x8
            int x = p;
            #pragma unroll
            for (int ofs = 1; ofs < 64; ofs <<= 1) {
                const int y = __shfl_up(x, ofs, 64);
                if (t >= ofs) x += y;
            }
            const int base = x - p;                 // local exclusive padded scan
            lcur[t] = base;
            loffL[t] = base;
        }
        __syncthreads();
        for (int e = w0 + t; e < w1; e += 1024) {
            const unsigned rec = ebuf[e];
            const int loc = (rec >> 17) & 63;
            const int pos = atomicAdd(&lcur[loc], 1);
            const int sv = (int)(rec & 0x1FFFFu);
            if (uselds) slds[pos] = sv; else srcs_g[gbase + pos] = sv;
        }
        for (int w = t; w < 512; w += 1024) {
            const int ln = w >> 3, k = w & 7;
            const int gn = bkt * 64 + ln;
            if (gn < n_nodes) {
                const int c = lcnt[ln];
                const int pad = (8 - (c & 7)) & 7;
                if (k < pad) {
                    const int pos = loffL[ln] + c + k;
                    if (uselds) slds[pos] = n_nodes; else srcs_g[gbase + pos] = n_nodes;
                }
            }
        }
        __syncthreads();

        // aggregation: 32 groups x 32 lanes, 2 nodes per group
        const int grp = t >> 5;
        const int l = t & 31;
        #pragma unroll
        for (int nn = 0; nn < 2; ++nn) {
            const int loc = grp * 2 + nn;
            const int gn = bkt * 64 + loc;
            if (gn >= n_nodes) continue;
            const int start = loffL[loc];
            const int deg = lcnt[loc];
            const int nb8 = (deg + 7) >> 3;
            float4 acc; acc.x = acc.y = acc.z = acc.w = 0.f;
            int myidx = 0;
            for (int b = 0; b < nb8; ++b) {
                const int q = b & 3;
                if (q == 0) {
                    const int ri = start + b * 8 + l;
                    myidx = uselds ? slds[ri] : srcs_g[gbase + ri];
                }
                ushort4 v[8];
                #pragma unroll
                for (int jj = 0; jj < 8; ++jj) {
                    const int s = __shfl(myidx, q * 8 + jj, 32);
                    v[jj] = hw4[(long)s * D4 + l];
                }
                #pragma unroll
                for (int jj = 0; jj < 8; ++jj) {
                    acc.x += bf2f(v[jj].x);
                    acc.y += bf2f(v[jj].y);
                    acc.z += bf2f(v[jj].z);
                    acc.w += bf2f(v[jj].w);
                }
            }
            const float nv = norm[gn];
            const float4 bs = ((const float4*)bias)[l];
            float4 o;
            o.x = acc.x * nv + bs.x;
            o.y = acc.y * nv + bs.y;
            o.z = acc.z * nv + bs.z;
            o.w = acc.w * nv + bs.w;
            ((float4*)out)[(long)gn * D4 + l] = o;
        }
    }
}

// ---------------------------------------------------------------------------
// TIER 2: round-1 multi-kernel path (kept as graceful fallback).
// ---------------------------------------------------------------------------
__global__ __launch_bounds__(1024) void hist_kernel(
    const int* __restrict__ dst, int* __restrict__ H,
    unsigned short* __restrict__ hwb, int n_edges, int n_nodes)
{
    __shared__ int lbh[MAXB];
    const int t = threadIdx.x;
    const int g = blockIdx.x;
    for (int i = t; i < MAXB; i += 1024) lbh[i] = 0;
    if (g == 0 && t < 32) {
        ushort4 z; z.x = z.y = z.z = z.w = 0;
        ((ushort4*)(hwb + (size_t)n_nodes * D))[t] = z;
    }
    __syncthreads();
    const int e0 = g * CHUNK;
    const int e1 = min(e0 + CHUNK, n_edges);
    for (int e = e0 + t; e < e1; e += 1024) {
        atomicAdd(&lbh[dst[e] >> 6], 1);
    }
    __syncthreads();
    for (int i = t; i < MAXB; i += 1024) {
        H[(size_t)g * MAXB + i] = lbh[i];
    }
}

__global__ __launch_bounds__(256) void colsum_kernel(
    const int* __restrict__ H, int* __restrict__ PS, int eb)
{
    const int col = blockIdx.x * 256 + threadIdx.x;
    const int seg = blockIdx.y;
    const int glen = (eb + NSEG - 1) / NSEG;
    const int g0 = seg * glen;
    const int g1 = min(g0 + glen, eb);
    int s = 0;
    for (int g = g0; g < g1; ++g) s += H[(size_t)g * MAXB + col];
    PS[seg * MAXB + col] = s;
}

__global__ __launch_bounds__(256) void bucket_scan_kernel(
    const int* __restrict__ PS, int* __restrict__ boff, int* __restrict__ bcur)
{
    __shared__ int tmp[256];
    const int t = threadIdx.x;
    int v[8];
    int s = 0;
    #pragma unroll
    for (int k = 0; k < 8; ++k) {
        const int i = t * 8 + k;
        int c = 0;
        #pragma unroll
        for (int sg = 0; sg < NSEG; ++sg) c += PS[sg * MAXB + i];
        v[k] = c; s += c;
    }
    tmp[t] = s;
    __syncthreads();
    for (int ofs = 1; ofs < 256; ofs <<= 1) {
        int x = (t >= ofs) ? tmp[t - ofs] : 0;
        __syncthreads();
        tmp[t] += x;
        __syncthreads();
    }
    int run = tmp[t] - s;
    #pragma unroll
    for (int k = 0; k < 8; ++k) {
        boff[t * 8 + k] = run;
        bcur[t * 8 + k] = run;
        run += v[k];
    }
    if (t == 255) boff[MAXB] = run;
}

__global__ __launch_bounds__(1024) void bscatter_kernel(
    const int* __restrict__ src, const int* __restrict__ dst,
    const int* __restrict__ H, int* __restrict__ bcur,
    unsigned int* __restrict__ ebuf, int n_edges)
{
    __shared__ int lbh[MAXB];
    __shared__ int lofs[MAXB];
    const int t = threadIdx.x;
    const int g = blockIdx.x;
    for (int i = t; i < MAXB; i += 1024) {
        lbh[i] = 0;
        const int c = H[(size_t)g * MAXB + i];
        lofs[i] = c ? atomicAdd(&bcur[i], c) : 0;
    }
    __syncthreads();
    const int e0 = g * CHUNK;
    const int e1 = min(e0 + CHUNK, n_edges);
    for (int e = e0 + t; e < e1; e += 1024) {
        const int d = dst[e];
        const int bk = d >> 6;
        const int r = atomicAdd(&lbh[bk], 1);
        ebuf[lofs[bk] + r] = (unsigned)src[e] | ((unsigned)(d & 63) << 17);
    }
}

__global__ __launch_bounds__(256) void fill_local_kernel(
    const unsigned int* __restrict__ ebuf, const int* __restrict__ boff,
    int* __restrict__ off, int* __restrict__ cnt,
    int* __restrict__ srcs, int n_nodes)
{
    __shared__ int lcnt[64];
    __shared__ int lcur[64];
    __shared__ int loff[64];
    const int t = threadIdx.x;
    const int b = blockIdx.x;
    const int gn0 = b * 64;
    if (t < 64) lcnt[t] = 0;
    __syncthreads();
    const int e0 = boff[b], e1 = boff[b + 1];
    for (int e = e0 + t; e < e1; e += 256) {
        atomicAdd(&lcnt[(ebuf[e] >> 17) & 63], 1);
    }
    __syncthreads();
    if (t < 64) {
        const int c = lcnt[t];
        const int p = (c + 7) & ~7;
        int x = p;
        #pragma unroll
        for (int ofs = 1; ofs < 64; ofs <<= 1) {
            const int y = __shfl_up(x, ofs, 64);
            if (t >= ofs) x += y;
        }
        const int base = boff[b] + b * 448 + (x - p);
        lcur[t] = base;
        loff[t] = base;
        const int gn = gn0 + t;
        if (gn < n_nodes) { cnt[gn] = c; off[gn] = base; }
    }
    __syncthreads();
    for (int e = e0 + t; e < e1; e += 256) {
        const unsigned rec = ebuf[e];
        const int loc = (rec >> 17) & 63;
        const int pos = atomicAdd(&lcur[loc], 1);
        srcs[pos] = (int)(rec & 0x1FFFFu);
    }
    for (int w = t; w < 512; w += 256) {
        const int ln = w >> 3, k = w & 7;
        const int gn = gn0 + ln;
        if (gn < n_nodes) {
            const int c = lcnt[ln];
            const int pad = (8 - (c & 7)) & 7;
            if (k < pad) srcs[loff[ln] + c + k] = n_nodes;
        }
    }
}

__global__ __launch_bounds__(256) void agg_kernel(
    const unsigned short* __restrict__ hwb, const int* __restrict__ srcs,
    const int* __restrict__ off, const int* __restrict__ cnt,
    const float* __restrict__ norm, const float* __restrict__ bias,
    float* __restrict__ out, int n_nodes)
{
    const int t = threadIdx.x;
    const int sub = t >> 5;
    const int lane32 = t & 31;
    const int node = blockIdx.x * 8 + sub;
    if (node >= n_nodes) return;

    const int start = off[node];
    const int deg = cnt[node];
    const int nb8 = (deg + 7) >> 3;

    const ushort4* hw4 = (const ushort4*)hwb;

    float4 acc; acc.x = acc.y = acc.z = acc.w = 0.0f;
    int myidx = 0;

    for (int b = 0; b < nb8; ++b) {
        const int q = b & 3;
        if (q == 0) myidx = srcs[start + b * 8 + lane32];
        ushort4 v[8];
        #pragma unroll
        for (int jj = 0; jj < 8; ++jj) {
            const int s = __shfl(myidx, q * 8 + jj, 32);
            v[jj] = hw4[(long)s * D4 + lane32];
        }
        #pragma unroll
        for (int jj = 0; jj < 8; ++jj) {
            acc.x += bf2f(v[jj].x);
            acc.y += bf2f(v[jj].y);
            acc.z += bf2f(v[jj].z);
            acc.w += bf2f(v[jj].w);
        }
    }

    const float nv = norm[node];
    const float4 bs = ((const float4*)bias)[lane32];
    float4 o;
    o.x = acc.x * nv + bs.x;
    o.y = acc.y * nv + bs.y;
    o.z = acc.z * nv + bs.z;
    o.w = acc.w * nv + bs.w;
    ((float4*)out)[(long)node * D4 + lane32] = o;
}

// ---------------------------------------------------------------------------
// TIER 3: atomic scatter fallback (ws too small / exotic sizes).
// ---------------------------------------------------------------------------
__global__ __launch_bounds__(256) void scatter_kernel(
    const unsigned short* __restrict__ hwb, const int* __restrict__ src,
    const int* __restrict__ dst, float* __restrict__ out, int n_edges)
{
    const int idx = blockIdx.x * 256 + threadIdx.x;
    if (idx >= n_edges * D4) return;
    const int e = idx >> 5;
    const int g = idx & 31;
    const int s = src[e];
    const int d = dst[e];
    const ushort4 v = ((const ushort4*)hwb)[(long)s * D4 + g];
    float* o = out + (long)d * D + g * 4;
    atomicAdd(o + 0, bf2f(v.x));
    atomicAdd(o + 1, bf2f(v.y));
    atomicAdd(o + 2, bf2f(v.z));
    atomicAdd(o + 3, bf2f(v.w));
}

__global__ __launch_bounds__(256) void finalize_kernel(
    float* __restrict__ out, const float* __restrict__ norm,
    const float* __restrict__ bias, int n_nodes)
{
    const int idx = blockIdx.x * 256 + threadIdx.x;
    if (idx >= n_nodes * D4) return;
    const int n = idx >> 5;
    const int g = idx & 31;
    float4 v = ((float4*)out)[idx];
    const float nv = norm[n];
    const float4 b = ((const float4*)bias)[g];
    v.x = v.x * nv + b.x;
    v.y = v.y * nv + b.y;
    v.z = v.z * nv + b.z;
    v.w = v.w * nv + b.w;
    ((float4*)out)[idx] = v;
}

extern "C" void kernel_launch(void* const* d_in, const int* in_sizes, int n_in,
                              void* d_out, int out_size, void* d_ws, size_t ws_size,
                              hipStream_t stream) {
    const float* h    = (const float*)d_in[0];
    const float* norm = (const float*)d_in[1];
    const int*   src  = (const int*)d_in[2];
    const int*   dst  = (const int*)d_in[3];
    const float* W    = (const float*)d_in[4];
    const float* bias = (const float*)d_in[5];
    float* out = (float*)d_out;

    const int n_nodes = in_sizes[1];
    const int n_edges = in_sizes[2];

    const int NBUCK = (n_nodes + 63) >> 6;             // buckets (64 nodes each)
    const int EB2   = (n_edges + CHUNK - 1) / CHUNK;   // tier-2 chunks
    const int EBC   = (n_edges + CHUNK_C - 1) / CHUNK_C; // coop chunks
    const int EBmax = (EB2 > EBC) ? EB2 : EBC;
    const int srcs_len = n_edges + 448 * NBUCK + 64;

    // ---- workspace layout (256B aligned) ----
    size_t p = 0;
    auto take = [&](size_t bytes) {
        size_t cur = p;
        p += (bytes + 255) & ~(size_t)255;
        return cur;
    };
    const size_t hwb_off  = take(((size_t)n_nodes + 1) * D * sizeof(unsigned short));
    const size_t cnt_off  = take((size_t)n_nodes * sizeof(int));
    const size_t off_off  = take((size_t)n_nodes * sizeof(int));
    const size_t srcs_off = take((size_t)srcs_len * sizeof(int));
    const size_t ebuf_off = take((size_t)n_edges * sizeof(unsigned int));
    const size_t boff_off = take((MAXB + 1) * sizeof(int));
    const size_t bcur_off = take(MAXB * sizeof(int));
    const size_t H_off    = take((size_t)EBmax * MAXB * sizeof(int));
    const size_t PS_off   = take((size_t)NSEG * MAXB * sizeof(int));
    const size_t SB_off   = take((size_t)NSEG * MAXB * sizeof(int));
    const size_t CO_off   = take((size_t)EBmax * MAXB * sizeof(int));
    const size_t needed = p;

    char* ws = (char*)d_ws;
    unsigned short* hwb = (unsigned short*)(ws + hwb_off);

    // 1) hwb = bf16((h @ W) * norm) via MFMA
    gemm_mfma_kernel<<<(n_nodes + 63) / 64, 256, 0, stream>>>(h, W, norm, hwb, n_nodes);

    // cooperative-residency check (host-side, cached)
    static int s_blocks_per_cu = -1;
    static int s_ncu = 0;
    if (s_blocks_per_cu < 0) {
        int nb = 0;
        if (hipOccupancyMaxActiveBlocksPerMultiprocessor(&nb, coop_kernel, 1024, 0) != hipSuccess)
            nb = 0;
        int dev = 0;
        hipGetDevice(&dev);
        int ncu = 0;
        if (hipDeviceGetAttribute(&ncu, hipDeviceAttributeMultiprocessorCount, dev) != hipSuccess)
            ncu = 0;
        s_blocks_per_cu = nb;
        s_ncu = ncu;
    }

    const bool ws_ok = (ws_size >= needed) && (NBUCK <= MAXB) && (n_nodes <= 131072);
    const bool coop_ok = ws_ok && EBC >= 16 && EBC <= 512 &&
                         (long)EBC <= (long)s_blocks_per_cu * (long)s_ncu;

    if (coop_ok) {
        int* cnt   = (int*)(ws + cnt_off);   (void)cnt;
        int* off   = (int*)(ws + off_off);   (void)off;
        int* srcs  = (int*)(ws + srcs_off);
        unsigned int* ebuf = (unsigned int*)(ws + ebuf_off);
        int* boff  = (int*)(ws + boff_off);
        int* H     = (int*)(ws + H_off);
        int* PS    = (int*)(ws + PS_off);
        int* SBp   = (int*)(ws + SB_off);
        int* CO    = (int*)(ws + CO_off);

        int ne = n_edges, nn = n_nodes, eb = EBC, nbk = NBUCK;
        void* args[] = {
            (void*)&src, (void*)&dst, (void*)&H, (void*)&PS, (void*)&SBp,
            (void*)&boff, (void*)&CO, (void*)&ebuf, (void*)&srcs, (void*)&hwb,
            (void*)&norm, (void*)&bias, (void*)&out,
            (void*)&ne, (void*)&nn, (void*)&eb, (void*)&nbk
        };
        hipLaunchCooperativeKernel((void*)coop_kernel, dim3(EBC), dim3(1024),
                                   args, 0, stream);
    } else if (ws_ok && EB2 <= 1024) {
        int* cnt   = (int*)(ws + cnt_off);
        int* off   = (int*)(ws + off_off);
        int* srcs  = (int*)(ws + srcs_off);
        unsigned int* ebuf = (unsigned int*)(ws + ebuf_off);
        int* boff  = (int*)(ws + boff_off);
        int* bcur  = (int*)(ws + bcur_off);
        int* H     = (int*)(ws + H_off);
        int* PS    = (int*)(ws + PS_off);

        hist_kernel<<<EB2, 1024, 0, stream>>>(dst, H, hwb, n_edges, n_nodes);
        colsum_kernel<<<dim3(MAXB / 256, NSEG), 256, 0, stream>>>(H, PS, EB2);
        bucket_scan_kernel<<<1, 256, 0, stream>>>(PS, boff, bcur);
        bscatter_kernel<<<EB2, 1024, 0, stream>>>(src, dst, H, bcur, ebuf, n_edges);
        fill_local_kernel<<<NBUCK, 256, 0, stream>>>(ebuf, boff, off, cnt, srcs, n_nodes);
        agg_kernel<<<(n_nodes + 7) / 8, 256, 0, stream>>>(hwb, srcs, off, cnt, norm, bias,
                                                          out, n_nodes);
    } else {
        hipMemsetAsync(d_out, 0, (size_t)out_size * sizeof(float), stream);
        const int work = n_edges * D4;
        scatter_kernel<<<(work + 255) / 256, 256, 0, stream>>>(hwb, src, dst, out, n_edges);
        const int work2 = n_nodes * D4;
        finalize_kernel<<<(work2 + 255) / 256, 256, 0, stream>>>(out, norm, bias, n_nodes);
    }
}

// Round 3
// 250.841 us; speedup vs baseline: 1.3178x; 1.0505x over previous
//
#include <hip/hip_runtime.h>
#include <hip/hip_bf16.h>

#define D 128            // D_IN == D_OUT == 128
#define D4 32            // D/4 float4s per row
#define CHUNK 3072       // edges per hist / bscatter block (1024 threads)
#define MAXB 2048        // max buckets => n_nodes <= 131072 for fast path
#define NSEG 8           // column-sum segments over the chunk axis
#define SL 4096          // LDS srcs-list capacity per bucket (ints, 16KB)

typedef __attribute__((ext_vector_type(8))) short bf16x8;
typedef __attribute__((ext_vector_type(8))) unsigned short ushort8;
typedef __attribute__((ext_vector_type(4))) float f32x4;

// float -> bf16 round-to-nearest-even
static __device__ __forceinline__ unsigned short f2bf(float f) {
    unsigned u = __float_as_uint(f);
    u += 0x7FFFu + ((u >> 16) & 1u);
    return (unsigned short)(u >> 16);
}
static __device__ __forceinline__ float bf2f(unsigned short u) {
    return __uint_as_float(((unsigned)u) << 16);
}

// ---------------------------------------------------------------------------
// One-time W transpose+convert: Wt[c][k] = bf16(W[k][c])  (c-major, 32KB).
// Removes per-gemm-block fp32 reads + 16K scalar converts/scalar LDS writes.
// ---------------------------------------------------------------------------
__global__ __launch_bounds__(256) void wcvt_kernel(
    const float* __restrict__ W, unsigned short* __restrict__ Wt)
{
    const int idx = blockIdx.x * 256 + threadIdx.x;   // float4 over 128x32
    const float4 w = ((const float4*)W)[idx];
    const int k = idx >> 5;
    const int c = (idx & 31) * 4;
    Wt[(c + 0) * 128 + k] = f2bf(w.x);
    Wt[(c + 1) * 128 + k] = f2bf(w.y);
    Wt[(c + 2) * 128 + k] = f2bf(w.z);
    Wt[(c + 3) * 128 + k] = f2bf(w.w);
}

// ---------------------------------------------------------------------------
// GEMM via bf16 MFMA: hwb[n,:] = bf16( (h[n,:] @ W) * norm[n] )
// 64-row tile/block, 256 thr = 4 waves; wave w handles rows [w*16,w*16+16),
// 8 col-tiles x 4 k-steps of v_mfma_f32_16x16x32_bf16.
// LDS rows padded to 136 ushorts (+16B) to break b128 bank conflicts.
// Bs now staged from pre-converted bf16 W^T via vector copies.
// ---------------------------------------------------------------------------
__global__ __launch_bounds__(256) void gemm_mfma_kernel(
    const float* __restrict__ h, const unsigned short* __restrict__ Wt,
    const float* __restrict__ norm, unsigned short* __restrict__ hwb,
    int n_nodes)
{
    __shared__ unsigned short As[64 * 136];    // [row][k] bf16, padded stride
    __shared__ unsigned short Bs[128 * 136];   // [col][k] bf16 (W^T), padded

    const int t = threadIdx.x;
    const int row0 = blockIdx.x * 64;

    #pragma unroll
    for (int i = 0; i < 8; ++i) {
        const int idx = t + 256 * i;           // ushort8 index over 128x16
        const int c = idx >> 4;                // col 0..127
        const int k8 = idx & 15;               // 8-ushort group 0..15
        const ushort8 w = ((const ushort8*)Wt)[idx];
        *(ushort8*)&Bs[c * 136 + k8 * 8] = w;
    }
    #pragma unroll
    for (int i = 0; i < 8; ++i) {
        const int idx = t + 256 * i;           // float4 index over 64x32
        const int r = idx >> 5;
        const int kq = idx & 31;
        long gr = row0 + r; if (gr >= n_nodes) gr = n_nodes - 1;
        const float4 a = ((const float4*)(h + gr * D))[kq];
        ushort4 o;
        o.x = f2bf(a.x); o.y = f2bf(a.y); o.z = f2bf(a.z); o.w = f2bf(a.w);
        *(ushort4*)&As[r * 136 + kq * 4] = o;
    }
    __syncthreads();

    const int wv = t >> 6;
    const int lane = t & 63;
    const int m = lane & 15;
    const int quad = lane >> 4;

    f32x4 acc[8];
    #pragma unroll
    for (int nt = 0; nt < 8; ++nt) { f32x4 z = {0.f, 0.f, 0.f, 0.f}; acc[nt] = z; }

    #pragma unroll
    for (int kt = 0; kt < 4; ++kt) {
        const bf16x8 af = *(const bf16x8*)&As[(wv * 16 + m) * 136 + kt * 32 + quad * 8];
        #pragma unroll
        for (int nt = 0; nt < 8; ++nt) {
            const bf16x8 bfr = *(const bf16x8*)&Bs[(nt * 16 + m) * 136 + kt * 32 + quad * 8];
            acc[nt] = __builtin_amdgcn_mfma_f32_16x16x32_bf16(af, bfr, acc[nt], 0, 0, 0);
        }
    }

    float nv[4];
    #pragma unroll
    for (int i = 0; i < 4; ++i) {
        const int gr = row0 + wv * 16 + quad * 4 + i;
        nv[i] = (gr < n_nodes) ? norm[gr] : 0.f;
    }
    #pragma unroll
    for (int nt = 0; nt < 8; ++nt) {
        #pragma unroll
        for (int i = 0; i < 4; ++i) {
            const int gr = row0 + wv * 16 + quad * 4 + i;
            if (gr < n_nodes)
                hwb[(size_t)gr * D + nt * 16 + m] = f2bf(acc[nt][i] * nv[i]);
        }
    }
}

// ---------------------------------------------------------------------------
// hist (1024 thr, CHUNK edges): LDS bucket histogram -> H[g][*] (coalesced).
// No global atomics. Block 0 zeroes the dummy hwb pad row.
// ---------------------------------------------------------------------------
__global__ __launch_bounds__(1024) void hist_kernel(
    const int* __restrict__ dst, int* __restrict__ H,
    unsigned short* __restrict__ hwb, int n_edges, int n_nodes)
{
    __shared__ int lbh[MAXB];
    const int t = threadIdx.x;
    const int g = blockIdx.x;
    for (int i = t; i < MAXB; i += 1024) lbh[i] = 0;
    if (g == 0 && t < 32) {
        ushort4 z; z.x = z.y = z.z = z.w = 0;
        ((ushort4*)(hwb + (size_t)n_nodes * D))[t] = z;
    }
    __syncthreads();
    const int e0 = g * CHUNK;
    const int e1 = min(e0 + CHUNK, n_edges);
    for (int e = e0 + t; e < e1; e += 1024) {
        atomicAdd(&lbh[dst[e] >> 6], 1);
    }
    __syncthreads();
    for (int i = t; i < MAXB; i += 1024) {
        H[(size_t)g * MAXB + i] = lbh[i];
    }
}

// ---------------------------------------------------------------------------
// colsum: segmented column sums of H -> PS[seg][bucket]. Coalesced.
// ---------------------------------------------------------------------------
__global__ __launch_bounds__(256) void colsum_kernel(
    const int* __restrict__ H, int* __restrict__ PS, int eb)
{
    const int col = blockIdx.x * 256 + threadIdx.x;
    const int seg = blockIdx.y;
    const int glen = (eb + NSEG - 1) / NSEG;
    const int g0 = seg * glen;
    const int g1 = min(g0 + glen, eb);
    int s = 0;
    for (int g = g0; g < g1; ++g) s += H[(size_t)g * MAXB + col];
    PS[seg * MAXB + col] = s;
}

// ---------------------------------------------------------------------------
// bucket_scan (1 block): sum PS segments -> exclusive scan -> boff, bcur.
// ---------------------------------------------------------------------------
__global__ __launch_bounds__(256) void bucket_scan_kernel(
    const int* __restrict__ PS, int* __restrict__ boff, int* __restrict__ bcur)
{
    __shared__ int tmp[256];
    const int t = threadIdx.x;
    int v[8];
    int s = 0;
    #pragma unroll
    for (int k = 0; k < 8; ++k) {
        const int i = t * 8 + k;
        int c = 0;
        #pragma unroll
        for (int sg = 0; sg < NSEG; ++sg) c += PS[sg * MAXB + i];
        v[k] = c; s += c;
    }
    tmp[t] = s;
    __syncthreads();
    for (int ofs = 1; ofs < 256; ofs <<= 1) {
        int x = (t >= ofs) ? tmp[t - ofs] : 0;
        __syncthreads();
        tmp[t] += x;
        __syncthreads();
    }
    int run = tmp[t] - s;
    #pragma unroll
    for (int k = 0; k < 8; ++k) {
        boff[t * 8 + k] = run;
        bcur[t * 8 + k] = run;
        run += v[k];
    }
    if (t == 255) boff[MAXB] = run;
}

// ---------------------------------------------------------------------------
// bscatter (1024 thr): reserve bucket windows via returning atomics, then
// LDS-ranked scatter of packed records (src | (dst&63)<<17) into ebuf.
// ---------------------------------------------------------------------------
__global__ __launch_bounds__(1024) void bscatter_kernel(
    const int* __restrict__ src, const int* __restrict__ dst,
    const int* __restrict__ H, int* __restrict__ bcur,
    unsigned int* __restrict__ ebuf, int n_edges)
{
    __shared__ int lbh[MAXB];
    __shared__ int lofs[MAXB];
    const int t = threadIdx.x;
    const int g = blockIdx.x;
    for (int i = t; i < MAXB; i += 1024) {
        lbh[i] = 0;
        const int c = H[(size_t)g * MAXB + i];
        lofs[i] = c ? atomicAdd(&bcur[i], c) : 0;
    }
    __syncthreads();
    const int e0 = g * CHUNK;
    const int e1 = min(e0 + CHUNK, n_edges);
    for (int e = e0 + t; e < e1; e += 1024) {
        const int d = dst[e];
        const int bk = d >> 6;
        const int r = atomicAdd(&lbh[bk], 1);
        ebuf[lofs[bk] + r] = (unsigned)src[e] | ((unsigned)(d & 63) << 17);
    }
}

// ---------------------------------------------------------------------------
// fillagg: one block per bucket (64 nodes, 256 thr). Count -> 64-lane padded
// wave-scan -> ranked scatter into LDS srcs list (global arena fallback) ->
// x8-padded register aggregation, out = agg*norm + bias. Fuses the old
// fill_local + agg, eliminating the srcs HBM round-trip. LDS 16.8KB, no
// launch-bounds min-wave clamp so the gather keeps full MLP (v[8] in flight).
// ---------------------------------------------------------------------------
__global__ __launch_bounds__(256) void fillagg_kernel(
    const unsigned int* __restrict__ ebuf, const int* __restrict__ boff,
    int* __restrict__ srcs_g, const unsigned short* __restrict__ hwb,
    const float* __restrict__ norm, const float* __restrict__ bias,
    float* __restrict__ out, int n_nodes)
{
    __shared__ int slds[SL];
    __shared__ int lcnt[64];
    __shared__ int lcur[64];
    __shared__ int loff[64];
    const int t = threadIdx.x;
    const int b = blockIdx.x;
    const int gn0 = b * 64;

    if (t < 64) lcnt[t] = 0;
    __syncthreads();
    const int w0 = boff[b], w1 = boff[b + 1];
    const int wlen = w1 - w0;
    const bool uselds = (wlen + 480) <= SL;     // pads(448) + margin(32)
    const int gbase = w0 + 448 * b;             // global arena fallback base

    for (int e = w0 + t; e < w1; e += 256) {
        atomicAdd(&lcnt[(ebuf[e] >> 17) & 63], 1);
    }
    __syncthreads();
    if (t < 64) {
        const int c = lcnt[t];
        const int p = (c + 7) & ~7;             // degree padded to x8
        int x = p;
        #pragma unroll
        for (int ofs = 1; ofs < 64; ofs <<= 1) {
            const int y = __shfl_up(x, ofs, 64);
            if (t >= ofs) x += y;
        }
        const int base = x - p;                 // bucket-local exclusive scan
        lcur[t] = base;
        loff[t] = base;
    }
    __syncthreads();
    for (int e = w0 + t; e < w1; e += 256) {
        const unsigned rec = ebuf[e];
        const int loc = (rec >> 17) & 63;
        const int pos = atomicAdd(&lcur[loc], 1);
        const int sv = (int)(rec & 0x1FFFFu);
        if (uselds) slds[pos] = sv; else srcs_g[gbase + pos] = sv;
    }
    for (int w = t; w < 512; w += 256) {
        const int ln = w >> 3, k = w & 7;
        const int gn = gn0 + ln;
        if (gn < n_nodes) {
            const int c = lcnt[ln];
            const int pad = (8 - (c & 7)) & 7;
            if (k < pad) {
                const int pos = loff[ln] + c + k;
                if (uselds) slds[pos] = n_nodes; else srcs_g[gbase + pos] = n_nodes;
            }
        }
    }
    __syncthreads();

    // aggregation: 8 groups x 32 lanes; each group handles 8 nodes
    const ushort4* hw4 = (const ushort4*)hwb;
    const int grp = t >> 5;
    const int l = t & 31;
    const float4 bs = ((const float4*)bias)[l];
    for (int nn = 0; nn < 8; ++nn) {
        const int loc = grp * 8 + nn;
        const int gn = gn0 + loc;
        if (gn >= n_nodes) continue;
        const int start = loff[loc];
        const int deg = lcnt[loc];
        const int nb8 = (deg + 7) >> 3;
        float4 acc; acc.x = acc.y = acc.z = acc.w = 0.f;
        int myidx = 0;
        for (int bb = 0; bb < nb8; ++bb) {
            const int q = bb & 3;
            if (q == 0) {
                const int ri = start + bb * 8 + l;
                myidx = uselds ? slds[ri] : srcs_g[gbase + ri];
            }
            ushort4 v[8];
            #pragma unroll
            for (int jj = 0; jj < 8; ++jj) {
                const int s = __shfl(myidx, q * 8 + jj, 32);
                v[jj] = hw4[(long)s * D4 + l];
            }
            #pragma unroll
            for (int jj = 0; jj < 8; ++jj) {
                acc.x += bf2f(v[jj].x);
                acc.y += bf2f(v[jj].y);
                acc.z += bf2f(v[jj].z);
                acc.w += bf2f(v[jj].w);
            }
        }
        const float nv = norm[gn];
        float4 o;
        o.x = acc.x * nv + bs.x;
        o.y = acc.y * nv + bs.y;
        o.z = acc.z * nv + bs.z;
        o.w = acc.w * nv + bs.w;
        ((float4*)out)[(long)gn * D4 + l] = o;
    }
}

// ---------------------------------------------------------------------------
// Fallback path: atomic scatter from bf16 hwb + finalize (ws too small).
// ---------------------------------------------------------------------------
__global__ __launch_bounds__(256) void scatter_kernel(
    const unsigned short* __restrict__ hwb, const int* __restrict__ src,
    const int* __restrict__ dst, float* __restrict__ out, int n_edges)
{
    const int idx = blockIdx.x * 256 + threadIdx.x;
    if (idx >= n_edges * D4) return;
    const int e = idx >> 5;
    const int g = idx & 31;
    const int s = src[e];
    const int d = dst[e];
    const ushort4 v = ((const ushort4*)hwb)[(long)s * D4 + g];
    float* o = out + (long)d * D + g * 4;
    atomicAdd(o + 0, bf2f(v.x));
    atomicAdd(o + 1, bf2f(v.y));
    atomicAdd(o + 2, bf2f(v.z));
    atomicAdd(o + 3, bf2f(v.w));
}

__global__ __launch_bounds__(256) void finalize_kernel(
    float* __restrict__ out, const float* __restrict__ norm,
    const float* __restrict__ bias, int n_nodes)
{
    const int idx = blockIdx.x * 256 + threadIdx.x;
    if (idx >= n_nodes * D4) return;
    const int n = idx >> 5;
    const int g = idx & 31;
    float4 v = ((float4*)out)[idx];
    const float nv = norm[n];
    const float4 b = ((const float4*)bias)[g];
    v.x = v.x * nv + b.x;
    v.y = v.y * nv + b.y;
    v.z = v.z * nv + b.z;
    v.w = v.w * nv + b.w;
    ((float4*)out)[idx] = v;
}

extern "C" void kernel_launch(void* const* d_in, const int* in_sizes, int n_in,
                              void* d_out, int out_size, void* d_ws, size_t ws_size,
                              hipStream_t stream) {
    const float* h    = (const float*)d_in[0];
    const float* norm = (const float*)d_in[1];
    const int*   src  = (const int*)d_in[2];
    const int*   dst  = (const int*)d_in[3];
    const float* W    = (const float*)d_in[4];
    const float* bias = (const float*)d_in[5];
    float* out = (float*)d_out;

    const int n_nodes = in_sizes[1];
    const int n_edges = in_sizes[2];

    const int NBUCK = (n_nodes + 63) >> 6;           // buckets (64 nodes each)
    const int EB    = (n_edges + CHUNK - 1) / CHUNK; // edge chunks
    const int srcs_len = n_edges + 448 * NBUCK + 64; // bucket-local pad bound

    // ---- workspace layout (256B aligned) ----
    size_t p = 0;
    auto take = [&](size_t bytes) {
        size_t cur = p;
        p += (bytes + 255) & ~(size_t)255;
        return cur;
    };
    const size_t hwb_off  = take(((size_t)n_nodes + 1) * D * sizeof(unsigned short));
    const size_t wt_off   = take((size_t)D * D * sizeof(unsigned short));
    const size_t srcs_off = take((size_t)srcs_len * sizeof(int));
    const size_t ebuf_off = take((size_t)n_edges * sizeof(unsigned int));
    const size_t boff_off = take((MAXB + 1) * sizeof(int));
    const size_t bcur_off = take(MAXB * sizeof(int));
    const size_t H_off    = take((size_t)EB * MAXB * sizeof(int));
    const size_t PS_off   = take((size_t)NSEG * MAXB * sizeof(int));
    const size_t needed = p;

    char* ws = (char*)d_ws;
    unsigned short* hwb = (unsigned short*)(ws + hwb_off);
    unsigned short* Wt  = (unsigned short*)(ws + wt_off);

    // 1) one-time W -> bf16 W^T, then hwb = bf16((h @ W) * norm) via MFMA
    wcvt_kernel<<<16, 256, 0, stream>>>(W, Wt);
    gemm_mfma_kernel<<<(n_nodes + 63) / 64, 256, 0, stream>>>(h, Wt, norm, hwb, n_nodes);

    if (ws_size >= needed && NBUCK <= MAXB && n_nodes <= 131072 && EB <= 1024) {
        int* srcs  = (int*)(ws + srcs_off);
        unsigned int* ebuf = (unsigned int*)(ws + ebuf_off);
        int* boff  = (int*)(ws + boff_off);
        int* bcur  = (int*)(ws + bcur_off);
        int* H     = (int*)(ws + H_off);
        int* PS    = (int*)(ws + PS_off);

        hist_kernel<<<EB, 1024, 0, stream>>>(dst, H, hwb, n_edges, n_nodes);
        colsum_kernel<<<dim3(MAXB / 256, NSEG), 256, 0, stream>>>(H, PS, EB);
        bucket_scan_kernel<<<1, 256, 0, stream>>>(PS, boff, bcur);
        bscatter_kernel<<<EB, 1024, 0, stream>>>(src, dst, H, bcur, ebuf, n_edges);
        fillagg_kernel<<<NBUCK, 256, 0, stream>>>(ebuf, boff, srcs, hwb, norm, bias,
                                                  out, n_nodes);
    } else {
        hipMemsetAsync(d_out, 0, (size_t)out_size * sizeof(float), stream);
        const int work = n_edges * D4;
        scatter_kernel<<<(work + 255) / 256, 256, 0, stream>>>(hwb, src, dst, out, n_edges);
        const int work2 = n_nodes * D4;
        finalize_kernel<<<(work2 + 255) / 256, 256, 0, stream>>>(out, norm, bias, n_nodes);
    }
}

// Round 4
// 247.097 us; speedup vs baseline: 1.3378x; 1.0152x over previous
//
#include <hip/hip_runtime.h>
#include <hip/hip_bf16.h>

#define D 128            // D_IN == D_OUT == 128
#define D4 32            // D/4 float4s per row
#define CHUNK 3072       // edges per hist / bscatter block (1024 threads)
#define MAXB 2048        // max buckets => n_nodes <= 131072 for fast path
#define NSEG 8           // column-sum segments over the chunk axis
#define SL 4096          // LDS srcs-list capacity per bucket (ints, 16KB)

typedef __attribute__((ext_vector_type(8))) short bf16x8;
typedef __attribute__((ext_vector_type(8))) unsigned short ushort8;
typedef __attribute__((ext_vector_type(4))) float f32x4;

// float -> bf16 round-to-nearest-even
static __device__ __forceinline__ unsigned short f2bf(float f) {
    unsigned u = __float_as_uint(f);
    u += 0x7FFFu + ((u >> 16) & 1u);
    return (unsigned short)(u >> 16);
}
static __device__ __forceinline__ float bf2f(unsigned short u) {
    return __uint_as_float(((unsigned)u) << 16);
}

// ---------------------------------------------------------------------------
// One-time W transpose+convert: Wt[c][k] = bf16(W[k][c])  (c-major, 32KB).
// ---------------------------------------------------------------------------
__global__ __launch_bounds__(256) void wcvt_kernel(
    const float* __restrict__ W, unsigned short* __restrict__ Wt)
{
    const int idx = blockIdx.x * 256 + threadIdx.x;   // float4 over 128x32
    const float4 w = ((const float4*)W)[idx];
    const int k = idx >> 5;
    const int c = (idx & 31) * 4;
    Wt[(c + 0) * 128 + k] = f2bf(w.x);
    Wt[(c + 1) * 128 + k] = f2bf(w.y);
    Wt[(c + 2) * 128 + k] = f2bf(w.z);
    Wt[(c + 3) * 128 + k] = f2bf(w.w);
}

// ---------------------------------------------------------------------------
// GEMM via bf16 MFMA: hwb[n,:] = bf16( (h[n,:] @ W) * norm[n] )
// 128-row tile/block, 512 thr = 8 waves; wave w handles rows [w*16,w*16+16).
// A fragments loaded DIRECTLY from global h (32B/lane, full 128B lines per
// wave per kt) + in-register bf16 convert -- no As LDS staging, one sync.
// Bs ([col][k] bf16 W^T) staged from pre-converted Wt; rows padded to 136.
// ---------------------------------------------------------------------------
__global__ __launch_bounds__(512) void gemm_mfma_kernel(
    const float* __restrict__ h, const unsigned short* __restrict__ Wt,
    const float* __restrict__ norm, unsigned short* __restrict__ hwb,
    int n_nodes)
{
    __shared__ unsigned short Bs[128 * 136];   // [col][k] bf16 (W^T), padded

    const int t = threadIdx.x;
    const int row0 = blockIdx.x * 128;

    #pragma unroll
    for (int i = 0; i < 4; ++i) {
        const int idx = t + 512 * i;           // ushort8 index over 128x16
        const int c = idx >> 4;                // col 0..127
        const int k8 = idx & 15;               // 8-ushort group 0..15
        *(ushort8*)&Bs[c * 136 + k8 * 8] = ((const ushort8*)Wt)[idx];
    }
    __syncthreads();

    const int wv = t >> 6;
    const int lane = t & 63;
    const int m = lane & 15;
    const int quad = lane >> 4;

    long gra = row0 + wv * 16 + m;             // A-fragment source row
    if (gra >= n_nodes) gra = n_nodes - 1;
    const float* hrow = h + gra * D;

    f32x4 acc[8];
    #pragma unroll
    for (int nt = 0; nt < 8; ++nt) { f32x4 z = {0.f, 0.f, 0.f, 0.f}; acc[nt] = z; }

    #pragma unroll
    for (int kt = 0; kt < 4; ++kt) {
        const float4 a0 = *(const float4*)(hrow + kt * 32 + quad * 8);
        const float4 a1 = *(const float4*)(hrow + kt * 32 + quad * 8 + 4);
        bf16x8 af;
        unsigned short* ap = (unsigned short*)&af;
        ap[0] = f2bf(a0.x); ap[1] = f2bf(a0.y); ap[2] = f2bf(a0.z); ap[3] = f2bf(a0.w);
        ap[4] = f2bf(a1.x); ap[5] = f2bf(a1.y); ap[6] = f2bf(a1.z); ap[7] = f2bf(a1.w);
        #pragma unroll
        for (int nt = 0; nt < 8; ++nt) {
            const bf16x8 bfr = *(const bf16x8*)&Bs[(nt * 16 + m) * 136 + kt * 32 + quad * 8];
            acc[nt] = __builtin_amdgcn_mfma_f32_16x16x32_bf16(af, bfr, acc[nt], 0, 0, 0);
        }
    }

    float nv[4];
    #pragma unroll
    for (int i = 0; i < 4; ++i) {
        const int gr = row0 + wv * 16 + quad * 4 + i;
        nv[i] = (gr < n_nodes) ? norm[gr] : 0.f;
    }
    #pragma unroll
    for (int nt = 0; nt < 8; ++nt) {
        #pragma unroll
        for (int i = 0; i < 4; ++i) {
            const int gr = row0 + wv * 16 + quad * 4 + i;
            if (gr < n_nodes)
                hwb[(size_t)gr * D + nt * 16 + m] = f2bf(acc[nt][i] * nv[i]);
        }
    }
}

// ---------------------------------------------------------------------------
// hist (1024 thr, CHUNK edges): LDS bucket histogram -> H[g][*] (coalesced).
// No global atomics. Block 0 zeroes the dummy hwb pad row.
// ---------------------------------------------------------------------------
__global__ __launch_bounds__(1024) void hist_kernel(
    const int* __restrict__ dst, int* __restrict__ H,
    unsigned short* __restrict__ hwb, int n_edges, int n_nodes)
{
    __shared__ int lbh[MAXB];
    const int t = threadIdx.x;
    const int g = blockIdx.x;
    for (int i = t; i < MAXB; i += 1024) lbh[i] = 0;
    if (g == 0 && t < 32) {
        ushort4 z; z.x = z.y = z.z = z.w = 0;
        ((ushort4*)(hwb + (size_t)n_nodes * D))[t] = z;
    }
    __syncthreads();
    const int e0 = g * CHUNK;
    const int e1 = min(e0 + CHUNK, n_edges);
    for (int e = e0 + t; e < e1; e += 1024) {
        atomicAdd(&lbh[dst[e] >> 6], 1);
    }
    __syncthreads();
    for (int i = t; i < MAXB; i += 1024) {
        H[(size_t)g * MAXB + i] = lbh[i];
    }
}

// ---------------------------------------------------------------------------
// colsum: segmented column sums of H -> PS[seg][bucket]. Coalesced.
// ---------------------------------------------------------------------------
__global__ __launch_bounds__(256) void colsum_kernel(
    const int* __restrict__ H, int* __restrict__ PS, int eb)
{
    const int col = blockIdx.x * 256 + threadIdx.x;
    const int seg = blockIdx.y;
    const int glen = (eb + NSEG - 1) / NSEG;
    const int g0 = seg * glen;
    const int g1 = min(g0 + glen, eb);
    int s = 0;
    for (int g = g0; g < g1; ++g) s += H[(size_t)g * MAXB + col];
    PS[seg * MAXB + col] = s;
}

// ---------------------------------------------------------------------------
// bucket_scan (1 block): sum PS segments -> exclusive bucket scan -> boff,
// plus per-segment bases SB[sg][b] (seed of each segment's chunk-scan).
// ---------------------------------------------------------------------------
__global__ __launch_bounds__(256) void bucket_scan_kernel(
    const int* __restrict__ PS, int* __restrict__ boff, int* __restrict__ SB)
{
    __shared__ int tmp[256];
    const int t = threadIdx.x;
    int v[8];
    int s = 0;
    #pragma unroll
    for (int k = 0; k < 8; ++k) {
        const int i = t * 8 + k;
        int c = 0;
        #pragma unroll
        for (int sg = 0; sg < NSEG; ++sg) c += PS[sg * MAXB + i];
        v[k] = c; s += c;
    }
    tmp[t] = s;
    __syncthreads();
    for (int ofs = 1; ofs < 256; ofs <<= 1) {
        int x = (t >= ofs) ? tmp[t - ofs] : 0;
        __syncthreads();
        tmp[t] += x;
        __syncthreads();
    }
    int run = tmp[t] - s;
    #pragma unroll
    for (int k = 0; k < 8; ++k) {
        const int i = t * 8 + k;
        boff[i] = run;
        int sb = run;
        #pragma unroll
        for (int sg = 0; sg < NSEG; ++sg) {
            SB[sg * MAXB + i] = sb;
            sb += PS[sg * MAXB + i];
        }
        run += v[k];
    }
    if (t == 255) boff[MAXB] = run;
}

// ---------------------------------------------------------------------------
// chunkscan: CO[g][b] = global base of (chunk g, bucket b) window, by serial
// run over the segment's chunk rows starting from SB. Replaces bscatter's
// 1M returning global atomics with coalesced streaming.
// ---------------------------------------------------------------------------
__global__ __launch_bounds__(256) void chunkscan_kernel(
    const int* __restrict__ H, const int* __restrict__ SB,
    int* __restrict__ CO, int eb)
{
    const int b = blockIdx.x * 256 + threadIdx.x;
    const int seg = blockIdx.y;
    const int glen = (eb + NSEG - 1) / NSEG;
    const int g0 = seg * glen;
    const int g1 = min(g0 + glen, eb);
    int run = SB[seg * MAXB + b];
    for (int g = g0; g < g1; ++g) {
        CO[(size_t)g * MAXB + b] = run;
        run += H[(size_t)g * MAXB + b];
    }
}

// ---------------------------------------------------------------------------
// bscatter (1024 thr): ATOMIC-FREE window bases from CO; LDS-ranked scatter
// of packed records (src | (dst&63)<<17) into bucket-major ebuf.
// ---------------------------------------------------------------------------
__global__ __launch_bounds__(1024) void bscatter_kernel(
    const int* __restrict__ src, const int* __restrict__ dst,
    const int* __restrict__ CO,
    unsigned int* __restrict__ ebuf, int n_edges)
{
    __shared__ int lbh[MAXB];
    __shared__ int lofs[MAXB];
    const int t = threadIdx.x;
    const int g = blockIdx.x;
    for (int i = t; i < MAXB; i += 1024) {
        lbh[i] = 0;
        lofs[i] = CO[(size_t)g * MAXB + i];
    }
    __syncthreads();
    const int e0 = g * CHUNK;
    const int e1 = min(e0 + CHUNK, n_edges);
    for (int e = e0 + t; e < e1; e += 1024) {
        const int d = dst[e];
        const int bk = d >> 6;
        const int r = atomicAdd(&lbh[bk], 1);
        ebuf[lofs[bk] + r] = (unsigned)src[e] | ((unsigned)(d & 63) << 17);
    }
}

// ---------------------------------------------------------------------------
// fillagg: one block per bucket (64 nodes, 256 thr). Count -> 64-lane padded
// wave-scan -> ranked scatter into LDS srcs list (global arena fallback) ->
// x8-padded register aggregation, out = agg*norm + bias.
// ---------------------------------------------------------------------------
__global__ __launch_bounds__(256) void fillagg_kernel(
    const unsigned int* __restrict__ ebuf, const int* __restrict__ boff,
    int* __restrict__ srcs_g, const unsigned short* __restrict__ hwb,
    const float* __restrict__ norm, const float* __restrict__ bias,
    float* __restrict__ out, int n_nodes)
{
    __shared__ int slds[SL];
    __shared__ int lcnt[64];
    __shared__ int lcur[64];
    __shared__ int loff[64];
    const int t = threadIdx.x;
    const int b = blockIdx.x;
    const int gn0 = b * 64;

    if (t < 64) lcnt[t] = 0;
    __syncthreads();
    const int w0 = boff[b], w1 = boff[b + 1];
    const int wlen = w1 - w0;
    const bool uselds = (wlen + 480) <= SL;     // pads(448) + margin(32)
    const int gbase = w0 + 448 * b;             // global arena fallback base

    for (int e = w0 + t; e < w1; e += 256) {
        atomicAdd(&lcnt[(ebuf[e] >> 17) & 63], 1);
    }
    __syncthreads();
    if (t < 64) {
        const int c = lcnt[t];
        const int p = (c + 7) & ~7;             // degree padded to x8
        int x = p;
        #pragma unroll
        for (int ofs = 1; ofs < 64; ofs <<= 1) {
            const int y = __shfl_up(x, ofs, 64);
            if (t >= ofs) x += y;
        }
        const int base = x - p;                 // bucket-local exclusive scan
        lcur[t] = base;
        loff[t] = base;
    }
    __syncthreads();
    for (int e = w0 + t; e < w1; e += 256) {
        const unsigned rec = ebuf[e];
        const int loc = (rec >> 17) & 63;
        const int pos = atomicAdd(&lcur[loc], 1);
        const int sv = (int)(rec & 0x1FFFFu);
        if (uselds) slds[pos] = sv; else srcs_g[gbase + pos] = sv;
    }
    for (int w = t; w < 512; w += 256) {
        const int ln = w >> 3, k = w & 7;
        const int gn = gn0 + ln;
        if (gn < n_nodes) {
            const int c = lcnt[ln];
            const int pad = (8 - (c & 7)) & 7;
            if (k < pad) {
                const int pos = loff[ln] + c + k;
                if (uselds) slds[pos] = n_nodes; else srcs_g[gbase + pos] = n_nodes;
            }
        }
    }
    __syncthreads();

    // aggregation: 8 groups x 32 lanes; each group handles 8 nodes
    const ushort4* hw4 = (const ushort4*)hwb;
    const int grp = t >> 5;
    const int l = t & 31;
    const float4 bs = ((const float4*)bias)[l];
    for (int nn = 0; nn < 8; ++nn) {
        const int loc = grp * 8 + nn;
        const int gn = gn0 + loc;
        if (gn >= n_nodes) continue;
        const int start = loff[loc];
        const int deg = lcnt[loc];
        const int nb8 = (deg + 7) >> 3;
        float4 acc; acc.x = acc.y = acc.z = acc.w = 0.f;
        int myidx = 0;
        for (int bb = 0; bb < nb8; ++bb) {
            const int q = bb & 3;
            if (q == 0) {
                const int ri = start + bb * 8 + l;
                myidx = uselds ? slds[ri] : srcs_g[gbase + ri];
            }
            ushort4 v[8];
            #pragma unroll
            for (int jj = 0; jj < 8; ++jj) {
                const int s = __shfl(myidx, q * 8 + jj, 32);
                v[jj] = hw4[(long)s * D4 + l];
            }
            #pragma unroll
            for (int jj = 0; jj < 8; ++jj) {
                acc.x += bf2f(v[jj].x);
                acc.y += bf2f(v[jj].y);
                acc.z += bf2f(v[jj].z);
                acc.w += bf2f(v[jj].w);
            }
        }
        const float nv = norm[gn];
        float4 o;
        o.x = acc.x * nv + bs.x;
        o.y = acc.y * nv + bs.y;
        o.z = acc.z * nv + bs.z;
        o.w = acc.w * nv + bs.w;
        ((float4*)out)[(long)gn * D4 + l] = o;
    }
}

// ---------------------------------------------------------------------------
// Fallback path: atomic scatter from bf16 hwb + finalize (ws too small).
// ---------------------------------------------------------------------------
__global__ __launch_bounds__(256) void scatter_kernel(
    const unsigned short* __restrict__ hwb, const int* __restrict__ src,
    const int* __restrict__ dst, float* __restrict__ out, int n_edges)
{
    const int idx = blockIdx.x * 256 + threadIdx.x;
    if (idx >= n_edges * D4) return;
    const int e = idx >> 5;
    const int g = idx & 31;
    const int s = src[e];
    const int d = dst[e];
    const ushort4 v = ((const ushort4*)hwb)[(long)s * D4 + g];
    float* o = out + (long)d * D + g * 4;
    atomicAdd(o + 0, bf2f(v.x));
    atomicAdd(o + 1, bf2f(v.y));
    atomicAdd(o + 2, bf2f(v.z));
    atomicAdd(o + 3, bf2f(v.w));
}

__global__ __launch_bounds__(256) void finalize_kernel(
    float* __restrict__ out, const float* __restrict__ norm,
    const float* __restrict__ bias, int n_nodes)
{
    const int idx = blockIdx.x * 256 + threadIdx.x;
    if (idx >= n_nodes * D4) return;
    const int n = idx >> 5;
    const int g = idx & 31;
    float4 v = ((float4*)out)[idx];
    const float nv = norm[n];
    const float4 b = ((const float4*)bias)[g];
    v.x = v.x * nv + b.x;
    v.y = v.y * nv + b.y;
    v.z = v.z * nv + b.z;
    v.w = v.w * nv + b.w;
    ((float4*)out)[idx] = v;
}

extern "C" void kernel_launch(void* const* d_in, const int* in_sizes, int n_in,
                              void* d_out, int out_size, void* d_ws, size_t ws_size,
                              hipStream_t stream) {
    const float* h    = (const float*)d_in[0];
    const float* norm = (const float*)d_in[1];
    const int*   src  = (const int*)d_in[2];
    const int*   dst  = (const int*)d_in[3];
    const float* W    = (const float*)d_in[4];
    const float* bias = (const float*)d_in[5];
    float* out = (float*)d_out;

    const int n_nodes = in_sizes[1];
    const int n_edges = in_sizes[2];

    const int NBUCK = (n_nodes + 63) >> 6;           // buckets (64 nodes each)
    const int EB    = (n_edges + CHUNK - 1) / CHUNK; // edge chunks
    const int srcs_len = n_edges + 448 * NBUCK + 64; // bucket-local pad bound

    // ---- workspace layout (256B aligned) ----
    size_t p = 0;
    auto take = [&](size_t bytes) {
        size_t cur = p;
        p += (bytes + 255) & ~(size_t)255;
        return cur;
    };
    const size_t hwb_off  = take(((size_t)n_nodes + 1) * D * sizeof(unsigned short));
    const size_t wt_off   = take((size_t)D * D * sizeof(unsigned short));
    const size_t srcs_off = take((size_t)srcs_len * sizeof(int));
    const size_t ebuf_off = take((size_t)n_edges * sizeof(unsigned int));
    const size_t boff_off = take((MAXB + 1) * sizeof(int));
    const size_t H_off    = take((size_t)EB * MAXB * sizeof(int));
    const size_t PS_off   = take((size_t)NSEG * MAXB * sizeof(int));
    const size_t SB_off   = take((size_t)NSEG * MAXB * sizeof(int));
    const size_t CO_off   = take((size_t)EB * MAXB * sizeof(int));
    const size_t needed = p;

    char* ws = (char*)d_ws;
    unsigned short* hwb = (unsigned short*)(ws + hwb_off);
    unsigned short* Wt  = (unsigned short*)(ws + wt_off);

    // 1) one-time W -> bf16 W^T, then hwb = bf16((h @ W) * norm) via MFMA
    wcvt_kernel<<<16, 256, 0, stream>>>(W, Wt);
    gemm_mfma_kernel<<<(n_nodes + 127) / 128, 512, 0, stream>>>(h, Wt, norm, hwb, n_nodes);

    if (ws_size >= needed && NBUCK <= MAXB && n_nodes <= 131072 && EB <= 1024) {
        int* srcs  = (int*)(ws + srcs_off);
        unsigned int* ebuf = (unsigned int*)(ws + ebuf_off);
        int* boff  = (int*)(ws + boff_off);
        int* H     = (int*)(ws + H_off);
        int* PS    = (int*)(ws + PS_off);
        int* SBp   = (int*)(ws + SB_off);
        int* CO    = (int*)(ws + CO_off);

        hist_kernel<<<EB, 1024, 0, stream>>>(dst, H, hwb, n_edges, n_nodes);
        colsum_kernel<<<dim3(MAXB / 256, NSEG), 256, 0, stream>>>(H, PS, EB);
        bucket_scan_kernel<<<1, 256, 0, stream>>>(PS, boff, SBp);
        chunkscan_kernel<<<dim3(MAXB / 256, NSEG), 256, 0, stream>>>(H, SBp, CO, EB);
        bscatter_kernel<<<EB, 1024, 0, stream>>>(src, dst, CO, ebuf, n_edges);
        fillagg_kernel<<<NBUCK, 256, 0, stream>>>(ebuf, boff, srcs, hwb, norm, bias,
                                                  out, n_nodes);
    } else {
        hipMemsetAsync(d_out, 0, (size_t)out_size * sizeof(float), stream);
        const int work = n_edges * D4;
        scatter_kernel<<<(work + 255) / 256, 256, 0, stream>>>(hwb, src, dst, out, n_edges);
        const int work2 = n_nodes * D4;
        finalize_kernel<<<(work2 + 255) / 256, 256, 0, stream>>>(out, norm, bias, n_nodes);
    }
}

// Round 5
// 235.367 us; speedup vs baseline: 1.4044x; 1.0498x over previous
//
#include <hip/hip_runtime.h>
#include <hip/hip_bf16.h>

#define D 128            // D_IN == D_OUT == 128
#define D4 32            // D/4 float4s per row
#define CHUNK 6144       // edges per hist / bscatter block (1024 threads)
#define MAXB 2048        // max buckets => n_nodes <= 131072 for fast path
#define NSEG 8           // scan segments over the chunk axis
#define SL 4096          // LDS srcs-list capacity per bucket (ints, 16KB)

typedef __attribute__((ext_vector_type(8))) short bf16x8;
typedef __attribute__((ext_vector_type(8))) unsigned short ushort8;
typedef __attribute__((ext_vector_type(4))) float f32x4;

// float -> bf16 round-to-nearest-even
static __device__ __forceinline__ unsigned short f2bf(float f) {
    unsigned u = __float_as_uint(f);
    u += 0x7FFFu + ((u >> 16) & 1u);
    return (unsigned short)(u >> 16);
}
static __device__ __forceinline__ float bf2f(unsigned short u) {
    return __uint_as_float(((unsigned)u) << 16);
}

// ---------------------------------------------------------------------------
// One-time W transpose+convert: Wt[c][k] = bf16(W[k][c])  (c-major, 32KB).
// ---------------------------------------------------------------------------
__global__ __launch_bounds__(256) void wcvt_kernel(
    const float* __restrict__ W, unsigned short* __restrict__ Wt)
{
    const int idx = blockIdx.x * 256 + threadIdx.x;   // float4 over 128x32
    const float4 w = ((const float4*)W)[idx];
    const int k = idx >> 5;
    const int c = (idx & 31) * 4;
    Wt[(c + 0) * 128 + k] = f2bf(w.x);
    Wt[(c + 1) * 128 + k] = f2bf(w.y);
    Wt[(c + 2) * 128 + k] = f2bf(w.z);
    Wt[(c + 3) * 128 + k] = f2bf(w.w);
}

// ---------------------------------------------------------------------------
// GEMM via bf16 MFMA: hwb[n,:] = bf16( (h[n,:] @ W) * norm[n] )
// 128-row tile/block, 512 thr = 8 waves. A fragments loaded directly from
// global h (in-register bf16 convert). Bs staged from pre-converted Wt.
// EPILOGUE: C routed through LDS (reusing Bs, dead after K-loop) so hwb is
// written as coalesced ushort8 full-line stores instead of 32 scalar 2B
// stores per thread (kills partial-sector write RMW).
// ---------------------------------------------------------------------------
__global__ __launch_bounds__(512) void gemm_mfma_kernel(
    const float* __restrict__ h, const unsigned short* __restrict__ Wt,
    const float* __restrict__ norm, unsigned short* __restrict__ hwb,
    int n_nodes)
{
    __shared__ unsigned short Bs[128 * 136];   // [col][k] bf16 (W^T); later C

    const int t = threadIdx.x;
    const int row0 = blockIdx.x * 128;

    #pragma unroll
    for (int i = 0; i < 4; ++i) {
        const int idx = t + 512 * i;           // ushort8 index over 128x16
        const int c = idx >> 4;                // col 0..127
        const int k8 = idx & 15;               // 8-ushort group 0..15
        *(ushort8*)&Bs[c * 136 + k8 * 8] = ((const ushort8*)Wt)[idx];
    }
    __syncthreads();

    const int wv = t >> 6;
    const int lane = t & 63;
    const int m = lane & 15;
    const int quad = lane >> 4;

    long gra = row0 + wv * 16 + m;             // A-fragment source row
    if (gra >= n_nodes) gra = n_nodes - 1;
    const float* hrow = h + gra * D;

    f32x4 acc[8];
    #pragma unroll
    for (int nt = 0; nt < 8; ++nt) { f32x4 z = {0.f, 0.f, 0.f, 0.f}; acc[nt] = z; }

    #pragma unroll
    for (int kt = 0; kt < 4; ++kt) {
        const float4 a0 = *(const float4*)(hrow + kt * 32 + quad * 8);
        const float4 a1 = *(const float4*)(hrow + kt * 32 + quad * 8 + 4);
        bf16x8 af;
        unsigned short* ap = (unsigned short*)&af;
        ap[0] = f2bf(a0.x); ap[1] = f2bf(a0.y); ap[2] = f2bf(a0.z); ap[3] = f2bf(a0.w);
        ap[4] = f2bf(a1.x); ap[5] = f2bf(a1.y); ap[6] = f2bf(a1.z); ap[7] = f2bf(a1.w);
        #pragma unroll
        for (int nt = 0; nt < 8; ++nt) {
            const bf16x8 bfr = *(const bf16x8*)&Bs[(nt * 16 + m) * 136 + kt * 32 + quad * 8];
            acc[nt] = __builtin_amdgcn_mfma_f32_16x16x32_bf16(af, bfr, acc[nt], 0, 0, 0);
        }
    }

    float nv[4];
    #pragma unroll
    for (int i = 0; i < 4; ++i) {
        const int gr = row0 + wv * 16 + quad * 4 + i;
        nv[i] = (gr < n_nodes) ? norm[gr] : 0.f;
    }

    __syncthreads();                           // all waves done reading Bs
    #pragma unroll
    for (int nt = 0; nt < 8; ++nt) {
        #pragma unroll
        for (int i = 0; i < 4; ++i) {
            const int r = wv * 16 + quad * 4 + i;     // 0..127 in-block row
            Bs[r * 136 + nt * 16 + m] = f2bf(acc[nt][i] * nv[i]);
        }
    }
    __syncthreads();

    #pragma unroll
    for (int i2 = 0; i2 < 4; ++i2) {
        const int idx = t + 512 * i2;          // ushort8 over 128x16
        const int r = idx >> 4;
        const int c8 = idx & 15;
        const int gr = row0 + r;
        if (gr < n_nodes)
            *(ushort8*)&hwb[(size_t)gr * D + c8 * 8] =
                *(const ushort8*)&Bs[r * 136 + c8 * 8];
    }
}

// ---------------------------------------------------------------------------
// hist (1024 thr, CHUNK edges): LDS bucket histogram -> H[g][*] (coalesced).
// No global atomics. Block 0 zeroes the dummy hwb pad row.
// ---------------------------------------------------------------------------
__global__ __launch_bounds__(1024) void hist_kernel(
    const int* __restrict__ dst, int* __restrict__ H,
    unsigned short* __restrict__ hwb, int n_edges, int n_nodes)
{
    __shared__ int lbh[MAXB];
    const int t = threadIdx.x;
    const int g = blockIdx.x;
    for (int i = t; i < MAXB; i += 1024) lbh[i] = 0;
    if (g == 0 && t < 32) {
        ushort4 z; z.x = z.y = z.z = z.w = 0;
        ((ushort4*)(hwb + (size_t)n_nodes * D))[t] = z;
    }
    __syncthreads();
    const int e0 = g * CHUNK;
    const int e1 = min(e0 + CHUNK, n_edges);
    for (int e = e0 + t; e < e1; e += 1024) {
        atomicAdd(&lbh[dst[e] >> 6], 1);
    }
    __syncthreads();
    for (int i = t; i < MAXB; i += 1024) {
        H[(size_t)g * MAXB + i] = lbh[i];
    }
}

// ---------------------------------------------------------------------------
// chunkscan_local: single H pass per (segment, bucket): local exclusive
// prefix over the segment's chunks -> CO (relative), segment total -> PS.
// Replaces the old colsum + chunkscan pair (one fewer launch + H stream).
// ---------------------------------------------------------------------------
__global__ __launch_bounds__(256) void chunkscan_local_kernel(
    const int* __restrict__ H, int* __restrict__ CO, int* __restrict__ PS,
    int eb)
{
    const int b = blockIdx.x * 256 + threadIdx.x;
    const int seg = blockIdx.y;
    const int glen = (eb + NSEG - 1) / NSEG;
    const int g0 = seg * glen;
    const int g1 = min(g0 + glen, eb);
    int run = 0;
    for (int g = g0; g < g1; ++g) {
        CO[(size_t)g * MAXB + b] = run;
        run += H[(size_t)g * MAXB + b];
    }
    PS[seg * MAXB + b] = run;
}

// ---------------------------------------------------------------------------
// bucket_scan (1 block): sum PS segments -> exclusive bucket scan -> boff,
// plus per-segment bases SB[sg][b].
// ---------------------------------------------------------------------------
__global__ __launch_bounds__(256) void bucket_scan_kernel(
    const int* __restrict__ PS, int* __restrict__ boff, int* __restrict__ SB)
{
    __shared__ int tmp[256];
    const int t = threadIdx.x;
    int v[8];
    int s = 0;
    #pragma unroll
    for (int k = 0; k < 8; ++k) {
        const int i = t * 8 + k;
        int c = 0;
        #pragma unroll
        for (int sg = 0; sg < NSEG; ++sg) c += PS[sg * MAXB + i];
        v[k] = c; s += c;
    }
    tmp[t] = s;
    __syncthreads();
    for (int ofs = 1; ofs < 256; ofs <<= 1) {
        int x = (t >= ofs) ? tmp[t - ofs] : 0;
        __syncthreads();
        tmp[t] += x;
        __syncthreads();
    }
    int run = tmp[t] - s;
    #pragma unroll
    for (int k = 0; k < 8; ++k) {
        const int i = t * 8 + k;
        boff[i] = run;
        int sb = run;
        #pragma unroll
        for (int sg = 0; sg < NSEG; ++sg) {
            SB[sg * MAXB + i] = sb;
            sb += PS[sg * MAXB + i];
        }
        run += v[k];
    }
    if (t == 255) boff[MAXB] = run;
}

// ---------------------------------------------------------------------------
// bscatter (1024 thr): atomic-free window bases = SB[seg][b] + CO[g][b];
// LDS-ranked scatter of packed records (src | (dst&63)<<17) into ebuf.
// ---------------------------------------------------------------------------
__global__ __launch_bounds__(1024) void bscatter_kernel(
    const int* __restrict__ src, const int* __restrict__ dst,
    const int* __restrict__ CO, const int* __restrict__ SB,
    unsigned int* __restrict__ ebuf, int n_edges, int eb)
{
    __shared__ int lbh[MAXB];
    __shared__ int lofs[MAXB];
    const int t = threadIdx.x;
    const int g = blockIdx.x;
    const int glen = (eb + NSEG - 1) / NSEG;
    const int seg = g / glen;
    for (int i = t; i < MAXB; i += 1024) {
        lbh[i] = 0;
        lofs[i] = SB[seg * MAXB + i] + CO[(size_t)g * MAXB + i];
    }
    __syncthreads();
    const int e0 = g * CHUNK;
    const int e1 = min(e0 + CHUNK, n_edges);
    for (int e = e0 + t; e < e1; e += 1024) {
        const int d = dst[e];
        const int bk = d >> 6;
        const int r = atomicAdd(&lbh[bk], 1);
        ebuf[lofs[bk] + r] = (unsigned)src[e] | ((unsigned)(d & 63) << 17);
    }
}

// ---------------------------------------------------------------------------
// fillagg: one block per bucket (64 nodes, 256 thr). Count -> 64-lane padded
// wave-scan -> ranked scatter into LDS srcs list (global arena fallback) ->
// x8-padded register aggregation, out = agg*norm + bias.
// ---------------------------------------------------------------------------
__global__ __launch_bounds__(256) void fillagg_kernel(
    const unsigned int* __restrict__ ebuf, const int* __restrict__ boff,
    int* __restrict__ srcs_g, const unsigned short* __restrict__ hwb,
    const float* __restrict__ norm, const float* __restrict__ bias,
    float* __restrict__ out, int n_nodes)
{
    __shared__ int slds[SL];
    __shared__ int lcnt[64];
    __shared__ int lcur[64];
    __shared__ int loff[64];
    const int t = threadIdx.x;
    const int b = blockIdx.x;
    const int gn0 = b * 64;

    if (t < 64) lcnt[t] = 0;
    __syncthreads();
    const int w0 = boff[b], w1 = boff[b + 1];
    const int wlen = w1 - w0;
    const bool uselds = (wlen + 480) <= SL;     // pads(448) + margin(32)
    const int gbase = w0 + 448 * b;             // global arena fallback base

    for (int e = w0 + t; e < w1; e += 256) {
        atomicAdd(&lcnt[(ebuf[e] >> 17) & 63], 1);
    }
    __syncthreads();
    if (t < 64) {
        const int c = lcnt[t];
        const int p = (c + 7) & ~7;             // degree padded to x8
        int x = p;
        #pragma unroll
        for (int ofs = 1; ofs < 64; ofs <<= 1) {
            const int y = __shfl_up(x, ofs, 64);
            if (t >= ofs) x += y;
        }
        const int base = x - p;                 // bucket-local exclusive scan
        lcur[t] = base;
        loff[t] = base;
    }
    __syncthreads();
    for (int e = w0 + t; e < w1; e += 256) {
        const unsigned rec = ebuf[e];
        const int loc = (rec >> 17) & 63;
        const int pos = atomicAdd(&lcur[loc], 1);
        const int sv = (int)(rec & 0x1FFFFu);
        if (uselds) slds[pos] = sv; else srcs_g[gbase + pos] = sv;
    }
    for (int w = t; w < 512; w += 256) {
        const int ln = w >> 3, k = w & 7;
        const int gn = gn0 + ln;
        if (gn < n_nodes) {
            const int c = lcnt[ln];
            const int pad = (8 - (c & 7)) & 7;
            if (k < pad) {
                const int pos = loff[ln] + c + k;
                if (uselds) slds[pos] = n_nodes; else srcs_g[gbase + pos] = n_nodes;
            }
        }
    }
    __syncthreads();

    // aggregation: 8 groups x 32 lanes; each group handles 8 nodes
    const ushort4* hw4 = (const ushort4*)hwb;
    const int grp = t >> 5;
    const int l = t & 31;
    const float4 bs = ((const float4*)bias)[l];
    for (int nn = 0; nn < 8; ++nn) {
        const int loc = grp * 8 + nn;
        const int gn = gn0 + loc;
        if (gn >= n_nodes) continue;
        const int start = loff[loc];
        const int deg = lcnt[loc];
        const int nb8 = (deg + 7) >> 3;
        float4 acc; acc.x = acc.y = acc.z = acc.w = 0.f;
        int myidx = 0;
        for (int bb = 0; bb < nb8; ++bb) {
            const int q = bb & 3;
            if (q == 0) {
                const int ri = start + bb * 8 + l;
                myidx = uselds ? slds[ri] : srcs_g[gbase + ri];
            }
            ushort4 v[8];
            #pragma unroll
            for (int jj = 0; jj < 8; ++jj) {
                const int s = __shfl(myidx, q * 8 + jj, 32);
                v[jj] = hw4[(long)s * D4 + l];
            }
            #pragma unroll
            for (int jj = 0; jj < 8; ++jj) {
                acc.x += bf2f(v[jj].x);
                acc.y += bf2f(v[jj].y);
                acc.z += bf2f(v[jj].z);
                acc.w += bf2f(v[jj].w);
            }
        }
        const float nv = norm[gn];
        float4 o;
        o.x = acc.x * nv + bs.x;
        o.y = acc.y * nv + bs.y;
        o.z = acc.z * nv + bs.z;
        o.w = acc.w * nv + bs.w;
        ((float4*)out)[(long)gn * D4 + l] = o;
    }
}

// ---------------------------------------------------------------------------
// Fallback path: atomic scatter from bf16 hwb + finalize (ws too small).
// ---------------------------------------------------------------------------
__global__ __launch_bounds__(256) void scatter_kernel(
    const unsigned short* __restrict__ hwb, const int* __restrict__ src,
    const int* __restrict__ dst, float* __restrict__ out, int n_edges)
{
    const int idx = blockIdx.x * 256 + threadIdx.x;
    if (idx >= n_edges * D4) return;
    const int e = idx >> 5;
    const int g = idx & 31;
    const int s = src[e];
    const int d = dst[e];
    const ushort4 v = ((const ushort4*)hwb)[(long)s * D4 + g];
    float* o = out + (long)d * D + g * 4;
    atomicAdd(o + 0, bf2f(v.x));
    atomicAdd(o + 1, bf2f(v.y));
    atomicAdd(o + 2, bf2f(v.z));
    atomicAdd(o + 3, bf2f(v.w));
}

__global__ __launch_bounds__(256) void finalize_kernel(
    float* __restrict__ out, const float* __restrict__ norm,
    const float* __restrict__ bias, int n_nodes)
{
    const int idx = blockIdx.x * 256 + threadIdx.x;
    if (idx >= n_nodes * D4) return;
    const int n = idx >> 5;
    const int g = idx & 31;
    float4 v = ((float4*)out)[idx];
    const float nv = norm[n];
    const float4 b = ((const float4*)bias)[g];
    v.x = v.x * nv + b.x;
    v.y = v.y * nv + b.y;
    v.z = v.z * nv + b.z;
    v.w = v.w * nv + b.w;
    ((float4*)out)[idx] = v;
}

extern "C" void kernel_launch(void* const* d_in, const int* in_sizes, int n_in,
                              void* d_out, int out_size, void* d_ws, size_t ws_size,
                              hipStream_t stream) {
    const float* h    = (const float*)d_in[0];
    const float* norm = (const float*)d_in[1];
    const int*   src  = (const int*)d_in[2];
    const int*   dst  = (const int*)d_in[3];
    const float* W    = (const float*)d_in[4];
    const float* bias = (const float*)d_in[5];
    float* out = (float*)d_out;

    const int n_nodes = in_sizes[1];
    const int n_edges = in_sizes[2];

    const int NBUCK = (n_nodes + 63) >> 6;           // buckets (64 nodes each)
    const int EB    = (n_edges + CHUNK - 1) / CHUNK; // edge chunks
    const int srcs_len = n_edges + 448 * NBUCK + 64; // bucket-local pad bound

    // ---- workspace layout (256B aligned) ----
    size_t p = 0;
    auto take = [&](size_t bytes) {
        size_t cur = p;
        p += (bytes + 255) & ~(size_t)255;
        return cur;
    };
    const size_t hwb_off  = take(((size_t)n_nodes + 1) * D * sizeof(unsigned short));
    const size_t wt_off   = take((size_t)D * D * sizeof(unsigned short));
    const size_t srcs_off = take((size_t)srcs_len * sizeof(int));
    const size_t ebuf_off = take((size_t)n_edges * sizeof(unsigned int));
    const size_t boff_off = take((MAXB + 1) * sizeof(int));
    const size_t H_off    = take((size_t)EB * MAXB * sizeof(int));
    const size_t PS_off   = take((size_t)NSEG * MAXB * sizeof(int));
    const size_t SB_off   = take((size_t)NSEG * MAXB * sizeof(int));
    const size_t CO_off   = take((size_t)EB * MAXB * sizeof(int));
    const size_t needed = p;

    char* ws = (char*)d_ws;
    unsigned short* hwb = (unsigned short*)(ws + hwb_off);
    unsigned short* Wt  = (unsigned short*)(ws + wt_off);

    // 1) one-time W -> bf16 W^T, then hwb = bf16((h @ W) * norm) via MFMA
    wcvt_kernel<<<16, 256, 0, stream>>>(W, Wt);
    gemm_mfma_kernel<<<(n_nodes + 127) / 128, 512, 0, stream>>>(h, Wt, norm, hwb, n_nodes);

    if (ws_size >= needed && NBUCK <= MAXB && n_nodes <= 131072 && EB <= 1024) {
        int* srcs  = (int*)(ws + srcs_off);
        unsigned int* ebuf = (unsigned int*)(ws + ebuf_off);
        int* boff  = (int*)(ws + boff_off);
        int* H     = (int*)(ws + H_off);
        int* PS    = (int*)(ws + PS_off);
        int* SBp   = (int*)(ws + SB_off);
        int* CO    = (int*)(ws + CO_off);

        hist_kernel<<<EB, 1024, 0, stream>>>(dst, H, hwb, n_edges, n_nodes);
        chunkscan_local_kernel<<<dim3(MAXB / 256, NSEG), 256, 0, stream>>>(H, CO, PS, EB);
        bucket_scan_kernel<<<1, 256, 0, stream>>>(PS, boff, SBp);
        bscatter_kernel<<<EB, 1024, 0, stream>>>(src, dst, CO, SBp, ebuf, n_edges, EB);
        fillagg_kernel<<<NBUCK, 256, 0, stream>>>(ebuf, boff, srcs, hwb, norm, bias,
                                                  out, n_nodes);
    } else {
        hipMemsetAsync(d_out, 0, (size_t)out_size * sizeof(float), stream);
        const int work = n_edges * D4;
        scatter_kernel<<<(work + 255) / 256, 256, 0, stream>>>(hwb, src, dst, out, n_edges);
        const int work2 = n_nodes * D4;
        finalize_kernel<<<(work2 + 255) / 256, 256, 0, stream>>>(out, norm, bias, n_nodes);
    }
}